// Round 1
// baseline (528.204 us; speedup 1.0000x reference)
//
#include <hip/hip_runtime.h>

#define B_ 2
#define L_ 2048
#define HEADS_ 16
#define DH_ 64
#define DM_ 1024
#define DBI_ 2048
#define DPROJ_ 7168
#define NTOK (B_*L_)      // 4096
#define DCAT (DM_ + DBI_) // 3072

typedef __bf16 bf16;
typedef __attribute__((ext_vector_type(8))) __bf16 bf16x8;
typedef __attribute__((ext_vector_type(4))) float floatx4;

// ---------------- transpose + cast f32 -> bf16 ----------------
// in: R x C row-major f32; out: C x R row-major bf16 (out[c][r] = in[r][c])
__global__ __launch_bounds__(256) void transpose_cast(const float* __restrict__ in,
                                                      bf16* __restrict__ out,
                                                      int R, int C) {
    __shared__ float tile[32][33];
    int c0 = blockIdx.x * 32, r0 = blockIdx.y * 32;
    int x = threadIdx.x & 31, y = threadIdx.x >> 5; // 32 x 8
    for (int i = 0; i < 32; i += 8) {
        tile[y + i][x] = in[(size_t)(r0 + y + i) * C + (c0 + x)];
    }
    __syncthreads();
    for (int i = 0; i < 32; i += 8) {
        out[(size_t)(c0 + y + i) * R + (r0 + x)] = (bf16)tile[x][y + i];
    }
}

// ---------------- in-LN + token shift -> xs (bf16) ----------------
__global__ __launch_bounds__(256) void ln_shift(const float* __restrict__ x,
                                                const float* __restrict__ g,
                                                const float* __restrict__ bb,
                                                bf16* __restrict__ xs) {
    int tok = blockIdx.x;
    int b = tok / L_, l = tok % L_;
    const float* row = x + (size_t)tok * DM_;
    float vals[4];
    float s = 0.f, s2 = 0.f;
    for (int i = 0; i < 4; i++) {
        float v = row[threadIdx.x + i * 256];
        vals[i] = v; s += v; s2 += v * v;
    }
    __shared__ float red[2][4];
    for (int o = 32; o; o >>= 1) { s += __shfl_xor(s, o); s2 += __shfl_xor(s2, o); }
    int w = threadIdx.x >> 6;
    if ((threadIdx.x & 63) == 0) { red[0][w] = s; red[1][w] = s2; }
    __syncthreads();
    s  = red[0][0] + red[0][1] + red[0][2] + red[0][3];
    s2 = red[1][0] + red[1][1] + red[1][2] + red[1][3];
    float mean = s * (1.f / DM_);
    float var  = s2 * (1.f / DM_) - mean * mean;
    float rstd = rsqrtf(var + 1e-5f);
    for (int i = 0; i < 4; i++) {
        int c = threadIdx.x + i * 256;
        float y = (vals[i] - mean) * rstd * g[c] + bb[c];
        int shift = (c < 256) ? 1 : ((c >= 896) ? 2 : 0);
        int dl = l + shift;
        if (dl < L_) xs[((size_t)b * L_ + dl) * DM_ + c] = (bf16)y;
        if (l == 0 && shift) {
            xs[((size_t)b * L_ + 0) * DM_ + c] = (bf16)0.f;
            if (shift == 2) xs[((size_t)b * L_ + 1) * DM_ + c] = (bf16)0.f;
        }
    }
}

// ---------------- NT GEMM: C[m][n] = sum_k A[m][k] * Bt[n][k] ----------------
// 64x64 block tile, 4 waves (2x2), each wave 32x32 via 2x2 mfma_f32_16x16x32_bf16
template <typename OutT>
__global__ __launch_bounds__(256) void gemm_nt(const bf16* __restrict__ A,
                                               const bf16* __restrict__ Bt,
                                               OutT* __restrict__ C,
                                               int M, int N, int K) {
    const int LD = 40;
    __shared__ bf16 As[64 * LD];
    __shared__ bf16 Bs[64 * LD];
    int m0 = blockIdx.x * 64, n0 = blockIdx.y * 64;
    int t = threadIdx.x;
    int lane = t & 63, wave = t >> 6;
    int wm = (wave >> 1) * 32, wn = (wave & 1) * 32;
    int quad = lane >> 4, mr = lane & 15;
    floatx4 acc[2][2] = {};
    int ar = t >> 2, ak = (t & 3) * 8; // staging: 64 rows x 32 k
    const bf16* Aptr = A + (size_t)(m0 + ar) * K + ak;
    const bf16* Bptr = Bt + (size_t)(n0 + ar) * K + ak;
    for (int k0 = 0; k0 < K; k0 += 32) {
        *(bf16x8*)&As[ar * LD + ak] = *(const bf16x8*)(Aptr + k0);
        *(bf16x8*)&Bs[ar * LD + ak] = *(const bf16x8*)(Bptr + k0);
        __syncthreads();
        bf16x8 af[2], bfv[2];
        for (int i = 0; i < 2; i++) {
            af[i]  = *(const bf16x8*)&As[(wm + i * 16 + mr) * LD + quad * 8];
            bfv[i] = *(const bf16x8*)&Bs[(wn + i * 16 + mr) * LD + quad * 8];
        }
        for (int i = 0; i < 2; i++)
            for (int j = 0; j < 2; j++)
                acc[i][j] = __builtin_amdgcn_mfma_f32_16x16x32_bf16(af[i], bfv[j], acc[i][j], 0, 0, 0);
        __syncthreads();
    }
    for (int i = 0; i < 2; i++)
        for (int j = 0; j < 2; j++)
            for (int r = 0; r < 4; r++) {
                int row = m0 + wm + i * 16 + quad * 4 + r;
                int col = n0 + wn + j * 16 + mr;
                C[(size_t)row * N + col] = (OutT)acc[i][j][r];
            }
}

// ---------------- mid-LN in place on bf16 h (row = 7168) ----------------
__global__ __launch_bounds__(256) void mid_ln(bf16* __restrict__ h,
                                              const float* __restrict__ g,
                                              const float* __restrict__ bb) {
    size_t base = (size_t)blockIdx.x * DPROJ_;
    float v[28];
    float s = 0.f, s2 = 0.f;
    for (int i = 0; i < 28; i++) {
        v[i] = (float)h[base + threadIdx.x + i * 256];
        s += v[i]; s2 += v[i] * v[i];
    }
    __shared__ float red[2][4];
    for (int o = 32; o; o >>= 1) { s += __shfl_xor(s, o); s2 += __shfl_xor(s2, o); }
    int w = threadIdx.x >> 6;
    if ((threadIdx.x & 63) == 0) { red[0][w] = s; red[1][w] = s2; }
    __syncthreads();
    s  = red[0][0] + red[0][1] + red[0][2] + red[0][3];
    s2 = red[1][0] + red[1][1] + red[1][2] + red[1][3];
    float mean = s * (1.f / DPROJ_);
    float var  = s2 * (1.f / DPROJ_) - mean * mean;
    float rstd = rsqrtf(var + 1e-5f);
    for (int i = 0; i < 28; i++) {
        int c = threadIdx.x + i * 256;
        h[base + c] = (bf16)((v[i] - mean) * rstd * g[c] + bb[c]);
    }
}

// ---------------- bilinear gate: A2[:,1024:3072] = p1 * p2 ----------------
__global__ __launch_bounds__(256) void gate(const bf16* __restrict__ h,
                                            bf16* __restrict__ A2) {
    size_t idx = (size_t)blockIdx.x * 256 + threadIdx.x; // 4096*2048
    size_t tok = idx >> 11, cc = idx & 2047;
    float a = (float)h[tok * DPROJ_ + 3 * DM_ + cc];
    float c = (float)h[tok * DPROJ_ + 3 * DM_ + DBI_ + cc];
    A2[tok * DCAT + DM_ + cc] = (bf16)(a * c);
}

// ---------------- flash attention (causal + alibi) ----------------
// grid: (L/64, HEADS, B). 4 waves; wave owns 16 query rows. 32-key tiles.
__global__ __launch_bounds__(256) void attn(const bf16* __restrict__ h,
                                            const float* __restrict__ slopes,
                                            bf16* __restrict__ A2) {
    int qb = blockIdx.x, hd = blockIdx.y, b = blockIdx.z;
    int q0 = qb * 64;
    int t = threadIdx.x, lane = t & 63, wave = t >> 6;
    int quad = lane >> 4, c = lane & 15;
    const int LDK = 88, LDV = 40, LDP = 40;
    __shared__ bf16 Ks[32 * LDK];      // [j][d]
    __shared__ bf16 Vs[64 * LDV];      // [d][j] (transposed)
    __shared__ bf16 Ps[4][16 * LDP];   // per-wave P 16x32
    const size_t rs = DPROJ_;
    const bf16* qbase = h + (size_t)b * L_ * rs + (size_t)hd * DH_;
    const bf16* kbase = qbase + DM_;
    const bf16* vbase = qbase + 2 * DM_;
    float slope = slopes[hd];

    bf16x8 qf[2];
    int qrow = q0 + wave * 16 + c;
    for (int db = 0; db < 2; db++)
        qf[db] = *(const bf16x8*)(qbase + (size_t)qrow * rs + db * 32 + quad * 8);

    floatx4 accO[4] = {};
    float m_r[4], l_r[4];
    int i_row[4];
    for (int r = 0; r < 4; r++) {
        m_r[r] = -INFINITY; l_r[r] = 0.f;
        i_row[r] = q0 + wave * 16 + quad * 4 + r;
    }
    int jend = q0 + 64;
    for (int j0 = 0; j0 < jend; j0 += 32) {
        { // stage K tile: 32 rows x 64 d
            int kk = t >> 3, dc = (t & 7) * 8;
            *(bf16x8*)&Ks[kk * LDK + dc] = *(const bf16x8*)(kbase + (size_t)(j0 + kk) * rs + dc);
        }
        { // stage V transposed: Vs[d][k]
            int d = t & 63;
            for (int kk2 = 0; kk2 < 8; kk2++) {
                int k = (t >> 6) + kk2 * 4;
                Vs[d * LDV + k] = vbase[(size_t)(j0 + k) * rs + d];
            }
        }
        __syncthreads();
        float sv[2][4];
        float mtile[4] = {-INFINITY, -INFINITY, -INFINITY, -INFINITY};
        for (int half = 0; half < 2; half++) {
            floatx4 sacc = {};
            for (int db = 0; db < 2; db++) {
                bf16x8 kf = *(const bf16x8*)&Ks[(half * 16 + c) * LDK + db * 32 + quad * 8];
                sacc = __builtin_amdgcn_mfma_f32_16x16x32_bf16(qf[db], kf, sacc, 0, 0, 0);
            }
            int j = j0 + half * 16 + c;
            for (int r = 0; r < 4; r++) {
                float sval = sacc[r] * 0.125f + slope * (float)j;
                sval = (j <= i_row[r]) ? sval : -INFINITY;
                sv[half][r] = sval;
                mtile[r] = fmaxf(mtile[r], sval);
            }
        }
        for (int r = 0; r < 4; r++) {
            float mm = mtile[r];
            mm = fmaxf(mm, __shfl_xor(mm, 1));
            mm = fmaxf(mm, __shfl_xor(mm, 2));
            mm = fmaxf(mm, __shfl_xor(mm, 4));
            mm = fmaxf(mm, __shfl_xor(mm, 8));
            mtile[r] = mm;
        }
        float pv[2][4];
        float alpha[4];
        for (int r = 0; r < 4; r++) {
            float mnew = fmaxf(m_r[r], mtile[r]);
            alpha[r] = __expf(m_r[r] - mnew);
            float psum = 0.f;
            for (int half = 0; half < 2; half++) {
                float p = __expf(sv[half][r] - mnew);
                pv[half][r] = p;
                psum += p;
            }
            psum += __shfl_xor(psum, 1);
            psum += __shfl_xor(psum, 2);
            psum += __shfl_xor(psum, 4);
            psum += __shfl_xor(psum, 8);
            l_r[r] = l_r[r] * alpha[r] + psum;
            m_r[r] = mnew;
        }
        for (int nt = 0; nt < 4; nt++)
            for (int r = 0; r < 4; r++)
                accO[nt][r] *= alpha[r];
        // P (C layout) -> LDS bf16 -> A layout
        bf16* pw = &Ps[wave][0];
        for (int r = 0; r < 4; r++) {
            int prow = quad * 4 + r;
            pw[prow * LDP + c]      = (bf16)pv[0][r];
            pw[prow * LDP + 16 + c] = (bf16)pv[1][r];
        }
        bf16x8 pf = *(const bf16x8*)&pw[c * LDP + quad * 8];
        for (int nt = 0; nt < 4; nt++) {
            bf16x8 vf = *(const bf16x8*)&Vs[(nt * 16 + c) * LDV + quad * 8];
            accO[nt] = __builtin_amdgcn_mfma_f32_16x16x32_bf16(pf, vf, accO[nt], 0, 0, 0);
        }
        __syncthreads();
    }
    float inv[4];
    for (int r = 0; r < 4; r++) inv[r] = 1.f / l_r[r];
    for (int nt = 0; nt < 4; nt++)
        for (int r = 0; r < 4; r++) {
            size_t row = (size_t)b * L_ + q0 + wave * 16 + quad * 4 + r;
            A2[row * DCAT + hd * DH_ + nt * 16 + c] = (bf16)(accO[nt][r] * inv[r]);
        }
}

// ---------------- out-LN: f32 in -> f32 out ----------------
__global__ __launch_bounds__(256) void out_ln_k(const float* __restrict__ in,
                                                const float* __restrict__ g,
                                                const float* __restrict__ bb,
                                                float* __restrict__ out) {
    size_t base = (size_t)blockIdx.x * DM_;
    float v[4];
    float s = 0.f, s2 = 0.f;
    for (int i = 0; i < 4; i++) {
        v[i] = in[base + threadIdx.x + i * 256];
        s += v[i]; s2 += v[i] * v[i];
    }
    __shared__ float red[2][4];
    for (int o = 32; o; o >>= 1) { s += __shfl_xor(s, o); s2 += __shfl_xor(s2, o); }
    int w = threadIdx.x >> 6;
    if ((threadIdx.x & 63) == 0) { red[0][w] = s; red[1][w] = s2; }
    __syncthreads();
    s  = red[0][0] + red[0][1] + red[0][2] + red[0][3];
    s2 = red[1][0] + red[1][1] + red[1][2] + red[1][3];
    float mean = s * (1.f / DM_);
    float var  = s2 * (1.f / DM_) - mean * mean;
    float rstd = rsqrtf(var + 1e-5f);
    for (int i = 0; i < 4; i++) {
        int c = threadIdx.x + i * 256;
        out[base + c] = (v[i] - mean) * rstd * g[c] + bb[c];
    }
}

extern "C" void kernel_launch(void* const* d_in, const int* in_sizes, int n_in,
                              void* d_out, int out_size, void* d_ws, size_t ws_size,
                              hipStream_t stream) {
    const float* x     = (const float*)d_in[0];
    const float* in_g  = (const float*)d_in[1];
    const float* in_b  = (const float*)d_in[2];
    const float* mid_g = (const float*)d_in[3];
    const float* mid_b = (const float*)d_in[4];
    const float* out_g = (const float*)d_in[5];
    const float* out_b = (const float*)d_in[6];
    const float* w_in  = (const float*)d_in[7];
    const float* w_out = (const float*)d_in[8];
    const float* slopes = (const float*)d_in[9];
    float* out = (float*)d_out;

    char* ws = (char*)d_ws;
    size_t off = 0;
    auto alloc = [&](size_t n) { char* p = ws + off; off += (n + 255) & ~(size_t)255; return p; };
    bf16* w_inT  = (bf16*)alloc((size_t)DPROJ_ * DM_ * 2);
    bf16* w_outT = (bf16*)alloc((size_t)DM_ * DCAT * 2);
    bf16* xs     = (bf16*)alloc((size_t)NTOK * DM_ * 2);
    bf16* h      = (bf16*)alloc((size_t)NTOK * DPROJ_ * 2);
    bf16* A2     = (bf16*)alloc((size_t)NTOK * DCAT * 2);
    float* oraw  = (float*)alloc((size_t)NTOK * DM_ * 4);

    hipLaunchKernelGGL(transpose_cast, dim3(DPROJ_ / 32, DM_ / 32), dim3(256), 0, stream,
                       w_in, w_inT, DM_, DPROJ_);
    hipLaunchKernelGGL(transpose_cast, dim3(DM_ / 32, DCAT / 32), dim3(256), 0, stream,
                       w_out, w_outT, DCAT, DM_);
    hipLaunchKernelGGL(ln_shift, dim3(NTOK), dim3(256), 0, stream, x, in_g, in_b, xs);
    hipLaunchKernelGGL(gemm_nt<bf16>, dim3(NTOK / 64, DPROJ_ / 64), dim3(256), 0, stream,
                       xs, w_inT, h, NTOK, DPROJ_, DM_);
    hipLaunchKernelGGL(mid_ln, dim3(NTOK), dim3(256), 0, stream, h, mid_g, mid_b);
    hipLaunchKernelGGL(gate, dim3((NTOK * DBI_) / 256), dim3(256), 0, stream, h, A2);
    hipLaunchKernelGGL(attn, dim3(L_ / 64, HEADS_, B_), dim3(256), 0, stream, h, slopes, A2);
    hipLaunchKernelGGL(gemm_nt<float>, dim3(NTOK / 64, DM_ / 64), dim3(256), 0, stream,
                       A2, w_outT, oraw, NTOK, DM_, DCAT);
    hipLaunchKernelGGL(out_ln_k, dim3(NTOK), dim3(256), 0, stream, oraw, out_g, out_b, out);
}

// Round 2
// 393.359 us; speedup vs baseline: 1.3428x; 1.3428x over previous
//
#include <hip/hip_runtime.h>

#define B_ 2
#define L_ 2048
#define HEADS_ 16
#define DH_ 64
#define DM_ 1024
#define DBI_ 2048
#define DPROJ_ 7168
#define NTOK (B_*L_)      // 4096
#define DCAT (DM_ + DBI_) // 3072

typedef __bf16 bf16;
typedef __attribute__((ext_vector_type(8))) __bf16 bf16x8;
typedef __attribute__((ext_vector_type(4))) float floatx4;

typedef __attribute__((address_space(1))) const void gptr_t;
typedef __attribute__((address_space(3))) void lptr_t;

__device__ __forceinline__ void g2l16(const void* g, void* l) {
    __builtin_amdgcn_global_load_lds((gptr_t*)g, (lptr_t*)l, 16, 0, 0);
}

// ---------------- transpose + cast f32 -> bf16 ----------------
__global__ __launch_bounds__(256) void transpose_cast(const float* __restrict__ in,
                                                      bf16* __restrict__ out,
                                                      int R, int C) {
    __shared__ float tile[32][33];
    int c0 = blockIdx.x * 32, r0 = blockIdx.y * 32;
    int x = threadIdx.x & 31, y = threadIdx.x >> 5;
    for (int i = 0; i < 32; i += 8) {
        tile[y + i][x] = in[(size_t)(r0 + y + i) * C + (c0 + x)];
    }
    __syncthreads();
    for (int i = 0; i < 32; i += 8) {
        out[(size_t)(c0 + y + i) * R + (r0 + x)] = (bf16)tile[x][y + i];
    }
}

// ---------------- in-LN + token shift -> xs (bf16) ----------------
__global__ __launch_bounds__(256) void ln_shift(const float* __restrict__ x,
                                                const float* __restrict__ g,
                                                const float* __restrict__ bb,
                                                bf16* __restrict__ xs) {
    int tok = blockIdx.x;
    int b = tok / L_, l = tok % L_;
    const float* row = x + (size_t)tok * DM_;
    float vals[4];
    float s = 0.f, s2 = 0.f;
    for (int i = 0; i < 4; i++) {
        float v = row[threadIdx.x + i * 256];
        vals[i] = v; s += v; s2 += v * v;
    }
    __shared__ float red[2][4];
    for (int o = 32; o; o >>= 1) { s += __shfl_xor(s, o); s2 += __shfl_xor(s2, o); }
    int w = threadIdx.x >> 6;
    if ((threadIdx.x & 63) == 0) { red[0][w] = s; red[1][w] = s2; }
    __syncthreads();
    s  = red[0][0] + red[0][1] + red[0][2] + red[0][3];
    s2 = red[1][0] + red[1][1] + red[1][2] + red[1][3];
    float mean = s * (1.f / DM_);
    float var  = s2 * (1.f / DM_) - mean * mean;
    float rstd = rsqrtf(var + 1e-5f);
    for (int i = 0; i < 4; i++) {
        int c = threadIdx.x + i * 256;
        float y = (vals[i] - mean) * rstd * g[c] + bb[c];
        int shift = (c < 256) ? 1 : ((c >= 896) ? 2 : 0);
        int dl = l + shift;
        if (dl < L_) xs[((size_t)b * L_ + dl) * DM_ + c] = (bf16)y;
        if (l == 0 && shift) {
            xs[((size_t)b * L_ + 0) * DM_ + c] = (bf16)0.f;
            if (shift == 2) xs[((size_t)b * L_ + 1) * DM_ + c] = (bf16)0.f;
        }
    }
}

// ---------------- m97-style NT GEMM: C[m][n] = sum_k A[m][k] * Bt[n][k] ----------------
// BK=32, 4 waves. TM=128: waves 2x2, wave tile 64x64 (4x4 accs).
// TM=64: waves 1x4, wave tile 64x32 (4x2 accs).
template <int TM, int TN, typename OutT>
__global__ __launch_bounds__(256) void gemm_nt2(const bf16* __restrict__ A,
                                                const bf16* __restrict__ Bt,
                                                OutT* __restrict__ C,
                                                int M, int N, int K) {
    constexpr int WR = TM / 64;          // wave rows: 2 or 1
    constexpr int WC = 4 / WR;           // wave cols: 2 or 4
    constexpr int NT = TN / WC / 16;     // ntiles per wave (4 or 2)
    constexpr int AISS = TM / 64;        // 16B-issues per thread for A
    constexpr int BISS = TN / 64;
    __shared__ bf16 As[TM * 32];
    __shared__ bf16 Bs[TN * 32];
    int m0 = blockIdx.x * TM, n0 = blockIdx.y * TN;
    int t = threadIdx.x, lane = t & 63, wave = t >> 6;
    int c = lane & 15, quad = lane >> 4;
    int wm = (wave / WC) * 64;
    int wn = (wave % WC) * (TN / WC);
    floatx4 acc[4][NT] = {};
    for (int k0 = 0; k0 < K; k0 += 32) {
        #pragma unroll
        for (int s = 0; s < AISS; s++) {
            int f = s * 256 + t;
            int row = f >> 2, kp = (f & 3) * 8;
            g2l16(A + (size_t)(m0 + row) * K + k0 + kp, &As[f * 8]);
        }
        #pragma unroll
        for (int s = 0; s < BISS; s++) {
            int f = s * 256 + t;
            int row = f >> 2, kp = (f & 3) * 8;
            g2l16(Bt + (size_t)(n0 + row) * K + k0 + kp, &Bs[f * 8]);
        }
        __syncthreads();
        bf16x8 af[4], bfr[NT];
        #pragma unroll
        for (int i = 0; i < 4; i++)
            af[i] = *(const bf16x8*)&As[(wm + i * 16 + c) * 32 + quad * 8];
        #pragma unroll
        for (int j = 0; j < NT; j++)
            bfr[j] = *(const bf16x8*)&Bs[(wn + j * 16 + c) * 32 + quad * 8];
        #pragma unroll
        for (int i = 0; i < 4; i++)
            #pragma unroll
            for (int j = 0; j < NT; j++)
                acc[i][j] = __builtin_amdgcn_mfma_f32_16x16x32_bf16(af[i], bfr[j], acc[i][j], 0, 0, 0);
        __syncthreads();
    }
    #pragma unroll
    for (int i = 0; i < 4; i++)
        #pragma unroll
        for (int j = 0; j < NT; j++)
            #pragma unroll
            for (int r = 0; r < 4; r++) {
                int row = m0 + wm + i * 16 + quad * 4 + r;
                int col = n0 + wn + j * 16 + c;
                C[(size_t)row * N + col] = (OutT)acc[i][j][r];
            }
}

// ---------------- mid-LN in place on bf16 h (row = 7168) ----------------
__global__ __launch_bounds__(256) void mid_ln(bf16* __restrict__ h,
                                              const float* __restrict__ g,
                                              const float* __restrict__ bb) {
    size_t base = (size_t)blockIdx.x * DPROJ_;
    float v[28];
    float s = 0.f, s2 = 0.f;
    for (int i = 0; i < 28; i++) {
        v[i] = (float)h[base + threadIdx.x + i * 256];
        s += v[i]; s2 += v[i] * v[i];
    }
    __shared__ float red[2][4];
    for (int o = 32; o; o >>= 1) { s += __shfl_xor(s, o); s2 += __shfl_xor(s2, o); }
    int w = threadIdx.x >> 6;
    if ((threadIdx.x & 63) == 0) { red[0][w] = s; red[1][w] = s2; }
    __syncthreads();
    s  = red[0][0] + red[0][1] + red[0][2] + red[0][3];
    s2 = red[1][0] + red[1][1] + red[1][2] + red[1][3];
    float mean = s * (1.f / DPROJ_);
    float var  = s2 * (1.f / DPROJ_) - mean * mean;
    float rstd = rsqrtf(var + 1e-5f);
    for (int i = 0; i < 28; i++) {
        int c = threadIdx.x + i * 256;
        h[base + c] = (bf16)((v[i] - mean) * rstd * g[c] + bb[c]);
    }
}

// ---------------- bilinear gate: A2[:,1024:3072] = p1 * p2 ----------------
__global__ __launch_bounds__(256) void gate(const bf16* __restrict__ h,
                                            bf16* __restrict__ A2) {
    size_t idx = (size_t)blockIdx.x * 256 + threadIdx.x;
    size_t tok = idx >> 11, cc = idx & 2047;
    float a = (float)h[tok * DPROJ_ + 3 * DM_ + cc];
    float c = (float)h[tok * DPROJ_ + 3 * DM_ + DBI_ + cc];
    A2[tok * DCAT + DM_ + cc] = (bf16)(a * c);
}

// ---------------- flash attention v2: balanced, 64-key tiles ----------------
// grid (16, HEADS, B); block processes q-tiles {x, 31-x} (33 key-iters const).
__global__ __launch_bounds__(256) void attn2(const bf16* __restrict__ h,
                                             const float* __restrict__ slopes,
                                             bf16* __restrict__ A2) {
    int hd = blockIdx.y, b = blockIdx.z;
    int t = threadIdx.x, lane = t & 63, wave = t >> 6;
    int quad = lane >> 4, c = lane & 15;
    __shared__ bf16 Ks[2 * 64 * 32];    // [kg][row][32] contiguous (global_load_lds)
    __shared__ bf16 Vs[64 * 72];        // [d][j] padded, conflict-free frags
    __shared__ bf16 Ps[4][16 * 72];     // per-wave P 16x64
    const size_t rs = DPROJ_;
    const bf16* base = h + (size_t)b * L_ * rs + (size_t)hd * DH_;
    const float LOG2E = 1.44269504f;
    float slopeL2 = slopes[hd] * LOG2E;
    const float qscale = 0.125f * LOG2E;

    for (int tt = 0; tt < 2; tt++) {
        int qt = (tt == 0) ? (int)blockIdx.x : (31 - (int)blockIdx.x);
        int q0 = qt * 64;
        bf16x8 qf[2];
        int qrow = q0 + wave * 16 + c;
        qf[0] = *(const bf16x8*)(base + (size_t)qrow * rs + quad * 8);
        qf[1] = *(const bf16x8*)(base + (size_t)qrow * rs + 32 + quad * 8);
        floatx4 accO[4] = {};
        float m_r[4], l_r[4];
        #pragma unroll
        for (int r = 0; r < 4; r++) { m_r[r] = -1e30f; l_r[r] = 0.f; }

        for (int j0 = 0; j0 <= q0; j0 += 64) {
            // stage K: [kg][row][32], lane-contiguous LDS
            #pragma unroll
            for (int s = 0; s < 2; s++) {
                int row = t >> 2, kp = (t & 3) * 8;
                g2l16(base + DM_ + (size_t)(j0 + row) * rs + s * 32 + kp,
                      &Ks[(s * 256 + t) * 8]);
            }
            // stage V transposed: Vs[d][j]; per-inst all lanes same d -> 32 banks
            {
                const bf16* vb = base + 2 * DM_;
                int j = t & 63;
                #pragma unroll
                for (int s = 0; s < 2; s++) {
                    int dp = (t >> 6) + 4 * s;   // 0..7
                    bf16x8 v = *(const bf16x8*)(vb + (size_t)(j0 + j) * rs + dp * 8);
                    #pragma unroll
                    for (int i = 0; i < 8; i++)
                        Vs[(dp * 8 + i) * 72 + j] = v[i];
                }
            }
            __syncthreads();

            float sv[4][4];
            bool diag = (j0 == q0);
            #pragma unroll
            for (int nt = 0; nt < 4; nt++) {
                floatx4 sacc = {};
                bf16x8 kf0 = *(const bf16x8*)&Ks[(nt * 16 + c) * 32 + quad * 8];
                bf16x8 kf1 = *(const bf16x8*)&Ks[2048 + (nt * 16 + c) * 32 + quad * 8];
                sacc = __builtin_amdgcn_mfma_f32_16x16x32_bf16(qf[0], kf0, sacc, 0, 0, 0);
                sacc = __builtin_amdgcn_mfma_f32_16x16x32_bf16(qf[1], kf1, sacc, 0, 0, 0);
                int j = j0 + nt * 16 + c;
                float al = slopeL2 * (float)j;
                #pragma unroll
                for (int r = 0; r < 4; r++) {
                    float s2v = sacc[r] * qscale + al;
                    if (diag) {
                        int i_row = q0 + wave * 16 + quad * 4 + r;
                        s2v = (j <= i_row) ? s2v : -1e30f;
                    }
                    sv[nt][r] = s2v;
                }
            }
            // online softmax (log2 domain)
            float alpha[4];
            #pragma unroll
            for (int r = 0; r < 4; r++) {
                float mt = fmaxf(fmaxf(sv[0][r], sv[1][r]), fmaxf(sv[2][r], sv[3][r]));
                mt = fmaxf(mt, __shfl_xor(mt, 1));
                mt = fmaxf(mt, __shfl_xor(mt, 2));
                mt = fmaxf(mt, __shfl_xor(mt, 4));
                mt = fmaxf(mt, __shfl_xor(mt, 8));
                float mnew = fmaxf(m_r[r], mt);
                alpha[r] = exp2f(m_r[r] - mnew);
                float ps = 0.f;
                #pragma unroll
                for (int nt = 0; nt < 4; nt++) {
                    float p = exp2f(sv[nt][r] - mnew);
                    sv[nt][r] = p;
                    ps += p;
                }
                ps += __shfl_xor(ps, 1);
                ps += __shfl_xor(ps, 2);
                ps += __shfl_xor(ps, 4);
                ps += __shfl_xor(ps, 8);
                l_r[r] = l_r[r] * alpha[r] + ps;
                m_r[r] = mnew;
            }
            // P: C-layout regs -> LDS -> A-layout frags (wave-private)
            bf16* pw = &Ps[wave][0];
            #pragma unroll
            for (int nt = 0; nt < 4; nt++)
                #pragma unroll
                for (int r = 0; r < 4; r++)
                    pw[(quad * 4 + r) * 72 + nt * 16 + c] = (bf16)sv[nt][r];
            #pragma unroll
            for (int nt = 0; nt < 4; nt++)
                #pragma unroll
                for (int r = 0; r < 4; r++)
                    accO[nt][r] *= alpha[r];
            bf16x8 pf0 = *(const bf16x8*)&pw[c * 72 + quad * 8];
            bf16x8 pf1 = *(const bf16x8*)&pw[c * 72 + 32 + quad * 8];
            #pragma unroll
            for (int nt = 0; nt < 4; nt++) {
                bf16x8 vf0 = *(const bf16x8*)&Vs[(nt * 16 + c) * 72 + quad * 8];
                bf16x8 vf1 = *(const bf16x8*)&Vs[(nt * 16 + c) * 72 + 32 + quad * 8];
                accO[nt] = __builtin_amdgcn_mfma_f32_16x16x32_bf16(pf0, vf0, accO[nt], 0, 0, 0);
                accO[nt] = __builtin_amdgcn_mfma_f32_16x16x32_bf16(pf1, vf1, accO[nt], 0, 0, 0);
            }
            __syncthreads();
        }
        #pragma unroll
        for (int r = 0; r < 4; r++) {
            float inv = 1.f / l_r[r];
            size_t row = (size_t)b * L_ + q0 + wave * 16 + quad * 4 + r;
            #pragma unroll
            for (int nt = 0; nt < 4; nt++)
                A2[row * DCAT + hd * DH_ + nt * 16 + c] = (bf16)(accO[nt][r] * inv);
        }
    }
}

// ---------------- out-LN: f32 in -> f32 out ----------------
__global__ __launch_bounds__(256) void out_ln_k(const float* __restrict__ in,
                                                const float* __restrict__ g,
                                                const float* __restrict__ bb,
                                                float* __restrict__ out) {
    size_t base = (size_t)blockIdx.x * DM_;
    float v[4];
    float s = 0.f, s2 = 0.f;
    for (int i = 0; i < 4; i++) {
        v[i] = in[base + threadIdx.x + i * 256];
        s += v[i]; s2 += v[i] * v[i];
    }
    __shared__ float red[2][4];
    for (int o = 32; o; o >>= 1) { s += __shfl_xor(s, o); s2 += __shfl_xor(s2, o); }
    int w = threadIdx.x >> 6;
    if ((threadIdx.x & 63) == 0) { red[0][w] = s; red[1][w] = s2; }
    __syncthreads();
    s  = red[0][0] + red[0][1] + red[0][2] + red[0][3];
    s2 = red[1][0] + red[1][1] + red[1][2] + red[1][3];
    float mean = s * (1.f / DM_);
    float var  = s2 * (1.f / DM_) - mean * mean;
    float rstd = rsqrtf(var + 1e-5f);
    for (int i = 0; i < 4; i++) {
        int c = threadIdx.x + i * 256;
        out[base + c] = (v[i] - mean) * rstd * g[c] + bb[c];
    }
}

extern "C" void kernel_launch(void* const* d_in, const int* in_sizes, int n_in,
                              void* d_out, int out_size, void* d_ws, size_t ws_size,
                              hipStream_t stream) {
    const float* x     = (const float*)d_in[0];
    const float* in_g  = (const float*)d_in[1];
    const float* in_b  = (const float*)d_in[2];
    const float* mid_g = (const float*)d_in[3];
    const float* mid_b = (const float*)d_in[4];
    const float* out_g = (const float*)d_in[5];
    const float* out_b = (const float*)d_in[6];
    const float* w_in  = (const float*)d_in[7];
    const float* w_out = (const float*)d_in[8];
    const float* slopes = (const float*)d_in[9];
    float* out = (float*)d_out;

    char* ws = (char*)d_ws;
    size_t off = 0;
    auto alloc = [&](size_t n) { char* p = ws + off; off += (n + 255) & ~(size_t)255; return p; };
    bf16* w_inT  = (bf16*)alloc((size_t)DPROJ_ * DM_ * 2);
    bf16* w_outT = (bf16*)alloc((size_t)DM_ * DCAT * 2);
    bf16* xs     = (bf16*)alloc((size_t)NTOK * DM_ * 2);
    bf16* h      = (bf16*)alloc((size_t)NTOK * DPROJ_ * 2);
    bf16* A2     = (bf16*)alloc((size_t)NTOK * DCAT * 2);
    float* oraw  = (float*)alloc((size_t)NTOK * DM_ * 4);

    hipLaunchKernelGGL(transpose_cast, dim3(DPROJ_ / 32, DM_ / 32), dim3(256), 0, stream,
                       w_in, w_inT, DM_, DPROJ_);
    hipLaunchKernelGGL(transpose_cast, dim3(DM_ / 32, DCAT / 32), dim3(256), 0, stream,
                       w_out, w_outT, DCAT, DM_);
    hipLaunchKernelGGL(ln_shift, dim3(NTOK), dim3(256), 0, stream, x, in_g, in_b, xs);
    hipLaunchKernelGGL((gemm_nt2<128, 128, bf16>), dim3(NTOK / 128, DPROJ_ / 128), dim3(256), 0, stream,
                       xs, w_inT, h, NTOK, DPROJ_, DM_);
    hipLaunchKernelGGL(mid_ln, dim3(NTOK), dim3(256), 0, stream, h, mid_g, mid_b);
    hipLaunchKernelGGL(gate, dim3((NTOK * DBI_) / 256), dim3(256), 0, stream, h, A2);
    hipLaunchKernelGGL(attn2, dim3(16, HEADS_, B_), dim3(256), 0, stream, h, slopes, A2);
    hipLaunchKernelGGL((gemm_nt2<64, 128, float>), dim3(NTOK / 64, DM_ / 128), dim3(256), 0, stream,
                       A2, w_outT, oraw, NTOK, DM_, DCAT);
    hipLaunchKernelGGL(out_ln_k, dim3(NTOK), dim3(256), 0, stream, oraw, out_g, out_b, out);
}

// Round 3
// 370.239 us; speedup vs baseline: 1.4267x; 1.0624x over previous
//
#include <hip/hip_runtime.h>

#define B_ 2
#define L_ 2048
#define HEADS_ 16
#define DH_ 64
#define DM_ 1024
#define DBI_ 2048
#define DPROJ_ 7168
#define NTOK (B_*L_)      // 4096
#define DCAT (DM_ + DBI_) // 3072

typedef __bf16 bf16;
typedef __attribute__((ext_vector_type(8))) __bf16 bf16x8;
typedef __attribute__((ext_vector_type(4))) float floatx4;

typedef __attribute__((address_space(1))) const void gptr_t;
typedef __attribute__((address_space(3))) void lptr_t;

__device__ __forceinline__ void g2l16(const void* g, void* l) {
    __builtin_amdgcn_global_load_lds((gptr_t*)g, (lptr_t*)l, 16, 0, 0);
}

// ---------------- transpose + cast f32 -> bf16 ----------------
__global__ __launch_bounds__(256) void transpose_cast(const float* __restrict__ in,
                                                      bf16* __restrict__ out,
                                                      int R, int C) {
    __shared__ float tile[32][33];
    int c0 = blockIdx.x * 32, r0 = blockIdx.y * 32;
    int x = threadIdx.x & 31, y = threadIdx.x >> 5;
    for (int i = 0; i < 32; i += 8) {
        tile[y + i][x] = in[(size_t)(r0 + y + i) * C + (c0 + x)];
    }
    __syncthreads();
    for (int i = 0; i < 32; i += 8) {
        out[(size_t)(c0 + y + i) * R + (r0 + x)] = (bf16)tile[x][y + i];
    }
}

// ---------------- in-LN + token shift -> xs (bf16) ----------------
__global__ __launch_bounds__(256) void ln_shift(const float* __restrict__ x,
                                                const float* __restrict__ g,
                                                const float* __restrict__ bb,
                                                bf16* __restrict__ xs) {
    int tok = blockIdx.x;
    int b = tok / L_, l = tok % L_;
    const float* row = x + (size_t)tok * DM_;
    float vals[4];
    float s = 0.f, s2 = 0.f;
    for (int i = 0; i < 4; i++) {
        float v = row[threadIdx.x + i * 256];
        vals[i] = v; s += v; s2 += v * v;
    }
    __shared__ float red[2][4];
    for (int o = 32; o; o >>= 1) { s += __shfl_xor(s, o); s2 += __shfl_xor(s2, o); }
    int w = threadIdx.x >> 6;
    if ((threadIdx.x & 63) == 0) { red[0][w] = s; red[1][w] = s2; }
    __syncthreads();
    s  = red[0][0] + red[0][1] + red[0][2] + red[0][3];
    s2 = red[1][0] + red[1][1] + red[1][2] + red[1][3];
    float mean = s * (1.f / DM_);
    float var  = s2 * (1.f / DM_) - mean * mean;
    float rstd = rsqrtf(var + 1e-5f);
    for (int i = 0; i < 4; i++) {
        int c = threadIdx.x + i * 256;
        float y = (vals[i] - mean) * rstd * g[c] + bb[c];
        int shift = (c < 256) ? 1 : ((c >= 896) ? 2 : 0);
        int dl = l + shift;
        if (dl < L_) xs[((size_t)b * L_ + dl) * DM_ + c] = (bf16)y;
        if (l == 0 && shift) {
            xs[((size_t)b * L_ + 0) * DM_ + c] = (bf16)0.f;
            if (shift == 2) xs[((size_t)b * L_ + 1) * DM_ + c] = (bf16)0.f;
        }
    }
}

// ---------------- m97-style NT GEMM ----------------
template <int TM, int TN, typename OutT>
__global__ __launch_bounds__(256) void gemm_nt2(const bf16* __restrict__ A,
                                                const bf16* __restrict__ Bt,
                                                OutT* __restrict__ C,
                                                int M, int N, int K) {
    constexpr int WR = TM / 64;
    constexpr int WC = 4 / WR;
    constexpr int NT = TN / WC / 16;
    constexpr int AISS = TM / 64;
    constexpr int BISS = TN / 64;
    __shared__ bf16 As[TM * 32];
    __shared__ bf16 Bs[TN * 32];
    int m0 = blockIdx.x * TM, n0 = blockIdx.y * TN;
    int t = threadIdx.x, lane = t & 63, wave = t >> 6;
    int c = lane & 15, quad = lane >> 4;
    int wm = (wave / WC) * 64;
    int wn = (wave % WC) * (TN / WC);
    floatx4 acc[4][NT] = {};
    for (int k0 = 0; k0 < K; k0 += 32) {
        #pragma unroll
        for (int s = 0; s < AISS; s++) {
            int f = s * 256 + t;
            int row = f >> 2, kp = (f & 3) * 8;
            g2l16(A + (size_t)(m0 + row) * K + k0 + kp, &As[f * 8]);
        }
        #pragma unroll
        for (int s = 0; s < BISS; s++) {
            int f = s * 256 + t;
            int row = f >> 2, kp = (f & 3) * 8;
            g2l16(Bt + (size_t)(n0 + row) * K + k0 + kp, &Bs[f * 8]);
        }
        __syncthreads();
        bf16x8 af[4], bfr[NT];
        #pragma unroll
        for (int i = 0; i < 4; i++)
            af[i] = *(const bf16x8*)&As[(wm + i * 16 + c) * 32 + quad * 8];
        #pragma unroll
        for (int j = 0; j < NT; j++)
            bfr[j] = *(const bf16x8*)&Bs[(wn + j * 16 + c) * 32 + quad * 8];
        #pragma unroll
        for (int i = 0; i < 4; i++)
            #pragma unroll
            for (int j = 0; j < NT; j++)
                acc[i][j] = __builtin_amdgcn_mfma_f32_16x16x32_bf16(af[i], bfr[j], acc[i][j], 0, 0, 0);
        __syncthreads();
    }
    #pragma unroll
    for (int i = 0; i < 4; i++)
        #pragma unroll
        for (int j = 0; j < NT; j++)
            #pragma unroll
            for (int r = 0; r < 4; r++) {
                int row = m0 + wm + i * 16 + quad * 4 + r;
                int col = n0 + wn + j * 16 + c;
                C[(size_t)row * N + col] = (OutT)acc[i][j][r];
            }
}

// ---------------- mid-LN fused: h -> Qp,Kp,Vn packed [b,h,L,64] + gated A2 ----------------
__global__ __launch_bounds__(256) void mid_ln_fused(const bf16* __restrict__ h,
                                                    const float* __restrict__ g,
                                                    const float* __restrict__ bb,
                                                    bf16* __restrict__ Qp,
                                                    bf16* __restrict__ Kp,
                                                    bf16* __restrict__ Vn,
                                                    bf16* __restrict__ A2) {
    int tok = blockIdx.x;
    int b = tok >> 11, l = tok & 2047;
    size_t base = (size_t)tok * DPROJ_;
    int t = threadIdx.x;
    float v[28];
    float s = 0.f, s2 = 0.f;
    for (int i = 0; i < 28; i++) {
        v[i] = (float)h[base + t + i * 256];
        s += v[i]; s2 += v[i] * v[i];
    }
    __shared__ float red[2][4];
    for (int o = 32; o; o >>= 1) { s += __shfl_xor(s, o); s2 += __shfl_xor(s2, o); }
    int w = t >> 6;
    if ((t & 63) == 0) { red[0][w] = s; red[1][w] = s2; }
    __syncthreads();
    s  = red[0][0] + red[0][1] + red[0][2] + red[0][3];
    s2 = red[1][0] + red[1][1] + red[1][2] + red[1][3];
    float mean = s * (1.f / DPROJ_);
    float var  = s2 * (1.f / DPROJ_) - mean * mean;
    float rstd = rsqrtf(var + 1e-5f);
    #pragma unroll
    for (int i = 0; i < 28; i++) {
        int c = t + i * 256;
        v[i] = (v[i] - mean) * rstd * g[c] + bb[c];
    }
    // q,k,v sections -> packed [b][h][l][d]
    #pragma unroll
    for (int i = 0; i < 12; i++) {
        int c = t + i * 256;
        int sec = c >> 10;                 // 0=q,1=k,2=v
        int cc = c & 1023;
        int hh = cc >> 6, d = cc & 63;
        size_t idx = (((size_t)b * HEADS_ + hh) * L_ + l) * DH_ + d;
        bf16* dst = (sec == 0) ? Qp : (sec == 1) ? Kp : Vn;
        dst[idx] = (bf16)v[i];
    }
    // gated p1*p2 -> A2[:, 1024:3072]
    #pragma unroll
    for (int i = 12; i < 20; i++) {
        int c = t + i * 256;               // 3072..5119
        A2[(size_t)tok * DCAT + DM_ + (c - 3 * DM_)] = (bf16)(v[i] * v[i + 8]);
    }
}

// ---------------- Vn [b,h,L,64] -> Vt [b,h,64,L] ----------------
__global__ __launch_bounds__(256) void vt_pack(const bf16* __restrict__ Vn,
                                               bf16* __restrict__ Vt) {
    __shared__ bf16 tile[32][33];
    int bh = blockIdx.z;
    const bf16* in = Vn + (size_t)bh * L_ * DH_;
    bf16* out = Vt + (size_t)bh * DH_ * L_;
    int l0 = blockIdx.x * 32, d0 = blockIdx.y * 32;
    int x = threadIdx.x & 31, y = threadIdx.x >> 5;
    for (int i = 0; i < 32; i += 8)
        tile[y + i][x] = in[(size_t)(l0 + y + i) * DH_ + d0 + x];
    __syncthreads();
    for (int i = 0; i < 32; i += 8)
        out[(size_t)(d0 + y + i) * L_ + l0 + x] = tile[x][y + i];
}

// ---------------- flash attention v3: packed inputs, g2l staging, 4 blocks/CU ----------------
// grid (32, HEADS, B). qt swizzled so the 4 co-resident blocks per CU sum to 66 iters.
__global__ __launch_bounds__(256, 4) void attn3(const bf16* __restrict__ Qp,
                                                const bf16* __restrict__ Kp,
                                                const bf16* __restrict__ Vt,
                                                const float* __restrict__ slopes,
                                                bf16* __restrict__ A2) {
    int hd = blockIdx.y, b = blockIdx.z;
    int lin = blockIdx.x + 32 * blockIdx.y + 512 * blockIdx.z;
    int xr = blockIdx.x;
    int qt = ((lin >> 8) & 1) ? (31 - xr) : xr;
    int q0 = qt * 64;
    int t = threadIdx.x, lane = t & 63, wave = t >> 6;
    int quad = lane >> 4, c = lane & 15;
    __shared__ bf16 Ks[2 * 64 * 32];   // [dhalf][row][32]
    __shared__ bf16 Vs[2 * 64 * 32];   // [jhalf][d][32]
    __shared__ bf16 Ps[4][16 * 72];
    int bh = b * HEADS_ + hd;
    const bf16* Qb = Qp + (size_t)bh * L_ * DH_;
    const bf16* Kb = Kp + (size_t)bh * L_ * DH_;
    const bf16* Vb = Vt + (size_t)bh * DH_ * L_;
    const float LOG2E = 1.44269504f;
    float slopeL2 = slopes[hd] * LOG2E;
    const float qscale = 0.125f * LOG2E;

    bf16x8 qf[2];
    int qrow = q0 + wave * 16 + c;
    qf[0] = *(const bf16x8*)(Qb + (size_t)qrow * DH_ + quad * 8);
    qf[1] = *(const bf16x8*)(Qb + (size_t)qrow * DH_ + 32 + quad * 8);
    floatx4 accO[4] = {};
    float m_r[4], l_r[4];
    #pragma unroll
    for (int r = 0; r < 4; r++) { m_r[r] = -1e30f; l_r[r] = 0.f; }

    int row = t >> 2, kp = (t & 3) * 8;
    for (int j0 = 0; j0 <= q0; j0 += 64) {
        #pragma unroll
        for (int s = 0; s < 2; s++) {
            g2l16(Kb + (size_t)(j0 + row) * DH_ + s * 32 + kp, &Ks[(s * 256 + t) * 8]);
            g2l16(Vb + (size_t)row * L_ + j0 + s * 32 + kp, &Vs[(s * 256 + t) * 8]);
        }
        __syncthreads();

        float sv[4][4];
        bool diag = (j0 == q0);
        #pragma unroll
        for (int nt = 0; nt < 4; nt++) {
            floatx4 sacc = {};
            bf16x8 kf0 = *(const bf16x8*)&Ks[(nt * 16 + c) * 32 + quad * 8];
            bf16x8 kf1 = *(const bf16x8*)&Ks[2048 + (nt * 16 + c) * 32 + quad * 8];
            sacc = __builtin_amdgcn_mfma_f32_16x16x32_bf16(qf[0], kf0, sacc, 0, 0, 0);
            sacc = __builtin_amdgcn_mfma_f32_16x16x32_bf16(qf[1], kf1, sacc, 0, 0, 0);
            int j = j0 + nt * 16 + c;
            float al = slopeL2 * (float)j;
            #pragma unroll
            for (int r = 0; r < 4; r++) {
                float s2v = sacc[r] * qscale + al;
                if (diag) {
                    int i_row = q0 + wave * 16 + quad * 4 + r;
                    s2v = (j <= i_row) ? s2v : -1e30f;
                }
                sv[nt][r] = s2v;
            }
        }
        float alpha[4];
        #pragma unroll
        for (int r = 0; r < 4; r++) {
            float mt = fmaxf(fmaxf(sv[0][r], sv[1][r]), fmaxf(sv[2][r], sv[3][r]));
            mt = fmaxf(mt, __shfl_xor(mt, 1));
            mt = fmaxf(mt, __shfl_xor(mt, 2));
            mt = fmaxf(mt, __shfl_xor(mt, 4));
            mt = fmaxf(mt, __shfl_xor(mt, 8));
            float mnew = fmaxf(m_r[r], mt);
            alpha[r] = exp2f(m_r[r] - mnew);
            float ps = 0.f;
            #pragma unroll
            for (int nt = 0; nt < 4; nt++) {
                float p = exp2f(sv[nt][r] - mnew);
                sv[nt][r] = p;
                ps += p;
            }
            ps += __shfl_xor(ps, 1);
            ps += __shfl_xor(ps, 2);
            ps += __shfl_xor(ps, 4);
            ps += __shfl_xor(ps, 8);
            l_r[r] = l_r[r] * alpha[r] + ps;
            m_r[r] = mnew;
        }
        bf16* pw = &Ps[wave][0];
        #pragma unroll
        for (int nt = 0; nt < 4; nt++)
            #pragma unroll
            for (int r = 0; r < 4; r++)
                pw[(quad * 4 + r) * 72 + nt * 16 + c] = (bf16)sv[nt][r];
        #pragma unroll
        for (int nt = 0; nt < 4; nt++)
            #pragma unroll
            for (int r = 0; r < 4; r++)
                accO[nt][r] *= alpha[r];
        bf16x8 pf0 = *(const bf16x8*)&pw[c * 72 + quad * 8];
        bf16x8 pf1 = *(const bf16x8*)&pw[c * 72 + 32 + quad * 8];
        #pragma unroll
        for (int nt = 0; nt < 4; nt++) {
            bf16x8 vf0 = *(const bf16x8*)&Vs[(nt * 16 + c) * 32 + quad * 8];
            bf16x8 vf1 = *(const bf16x8*)&Vs[2048 + (nt * 16 + c) * 32 + quad * 8];
            accO[nt] = __builtin_amdgcn_mfma_f32_16x16x32_bf16(pf0, vf0, accO[nt], 0, 0, 0);
            accO[nt] = __builtin_amdgcn_mfma_f32_16x16x32_bf16(pf1, vf1, accO[nt], 0, 0, 0);
        }
        __syncthreads();
    }
    #pragma unroll
    for (int r = 0; r < 4; r++) {
        float inv = 1.f / l_r[r];
        size_t orow = (size_t)b * L_ + q0 + wave * 16 + quad * 4 + r;
        #pragma unroll
        for (int nt = 0; nt < 4; nt++)
            A2[orow * DCAT + hd * DH_ + nt * 16 + c] = (bf16)(accO[nt][r] * inv);
    }
}

// ---------------- out-LN: f32 in -> f32 out ----------------
__global__ __launch_bounds__(256) void out_ln_k(const float* __restrict__ in,
                                                const float* __restrict__ g,
                                                const float* __restrict__ bb,
                                                float* __restrict__ out) {
    size_t base = (size_t)blockIdx.x * DM_;
    float v[4];
    float s = 0.f, s2 = 0.f;
    for (int i = 0; i < 4; i++) {
        v[i] = in[base + threadIdx.x + i * 256];
        s += v[i]; s2 += v[i] * v[i];
    }
    __shared__ float red[2][4];
    for (int o = 32; o; o >>= 1) { s += __shfl_xor(s, o); s2 += __shfl_xor(s2, o); }
    int w = threadIdx.x >> 6;
    if ((threadIdx.x & 63) == 0) { red[0][w] = s; red[1][w] = s2; }
    __syncthreads();
    s  = red[0][0] + red[0][1] + red[0][2] + red[0][3];
    s2 = red[1][0] + red[1][1] + red[1][2] + red[1][3];
    float mean = s * (1.f / DM_);
    float var  = s2 * (1.f / DM_) - mean * mean;
    float rstd = rsqrtf(var + 1e-5f);
    for (int i = 0; i < 4; i++) {
        int c = threadIdx.x + i * 256;
        out[base + c] = (v[i] - mean) * rstd * g[c] + bb[c];
    }
}

extern "C" void kernel_launch(void* const* d_in, const int* in_sizes, int n_in,
                              void* d_out, int out_size, void* d_ws, size_t ws_size,
                              hipStream_t stream) {
    const float* x     = (const float*)d_in[0];
    const float* in_g  = (const float*)d_in[1];
    const float* in_b  = (const float*)d_in[2];
    const float* mid_g = (const float*)d_in[3];
    const float* mid_b = (const float*)d_in[4];
    const float* out_g = (const float*)d_in[5];
    const float* out_b = (const float*)d_in[6];
    const float* w_in  = (const float*)d_in[7];
    const float* w_out = (const float*)d_in[8];
    const float* slopes = (const float*)d_in[9];
    float* out = (float*)d_out;

    char* ws = (char*)d_ws;
    size_t off = 0;
    auto alloc = [&](size_t n) { char* p = ws + off; off += (n + 255) & ~(size_t)255; return p; };
    bf16* w_inT  = (bf16*)alloc((size_t)DPROJ_ * DM_ * 2);   // 14.7 MB
    bf16* w_outT = (bf16*)alloc((size_t)DM_ * DCAT * 2);     // 6.3 MB
    bf16* xs     = (bf16*)alloc((size_t)NTOK * DM_ * 2);     // 8.4 MB (reused as Vt)
    bf16* h      = (bf16*)alloc((size_t)NTOK * DPROJ_ * 2);  // 58.7 MB
    bf16* A2     = (bf16*)alloc((size_t)NTOK * DCAT * 2);    // 25.2 MB
    float* oraw  = (float*)alloc((size_t)NTOK * DM_ * 4);    // 16.8 MB (first half reused as Vn)
    bf16* Qp     = (bf16*)alloc((size_t)NTOK * DM_ * 2);     // 8.4 MB
    bf16* Kp     = (bf16*)alloc((size_t)NTOK * DM_ * 2);     // 8.4 MB
    bf16* Vt = xs;          // xs dead after gemm1
    bf16* Vn = (bf16*)oraw; // oraw not written until gemm2 (after attn3)

    hipLaunchKernelGGL(transpose_cast, dim3(DPROJ_ / 32, DM_ / 32), dim3(256), 0, stream,
                       w_in, w_inT, DM_, DPROJ_);
    hipLaunchKernelGGL(transpose_cast, dim3(DM_ / 32, DCAT / 32), dim3(256), 0, stream,
                       w_out, w_outT, DCAT, DM_);
    hipLaunchKernelGGL(ln_shift, dim3(NTOK), dim3(256), 0, stream, x, in_g, in_b, xs);
    hipLaunchKernelGGL((gemm_nt2<128, 128, bf16>), dim3(NTOK / 128, DPROJ_ / 128), dim3(256), 0, stream,
                       xs, w_inT, h, NTOK, DPROJ_, DM_);
    hipLaunchKernelGGL(mid_ln_fused, dim3(NTOK), dim3(256), 0, stream, h, mid_g, mid_b,
                       Qp, Kp, Vn, A2);
    hipLaunchKernelGGL(vt_pack, dim3(L_ / 32, DH_ / 32, B_ * HEADS_), dim3(256), 0, stream, Vn, Vt);
    hipLaunchKernelGGL(attn3, dim3(32, HEADS_, B_), dim3(256), 0, stream, Qp, Kp, Vt, slopes, A2);
    hipLaunchKernelGGL((gemm_nt2<64, 128, float>), dim3(NTOK / 64, DM_ / 128), dim3(256), 0, stream,
                       A2, w_outT, oraw, NTOK, DM_, DCAT);
    hipLaunchKernelGGL(out_ln_k, dim3(NTOK), dim3(256), 0, stream, oraw, out_g, out_b, out);
}

// Round 5
// 357.075 us; speedup vs baseline: 1.4793x; 1.0369x over previous
//
#include <hip/hip_runtime.h>

#define B_ 2
#define L_ 2048
#define HEADS_ 16
#define DH_ 64
#define DM_ 1024
#define DBI_ 2048
#define DPROJ_ 7168
#define NTOK (B_*L_)      // 4096
#define DCAT (DM_ + DBI_) // 3072

typedef __bf16 bf16;
typedef __attribute__((ext_vector_type(8))) __bf16 bf16x8;
typedef __attribute__((ext_vector_type(4))) float floatx4;

typedef __attribute__((address_space(1))) const void gptr_t;
typedef __attribute__((address_space(3))) void lptr_t;

__device__ __forceinline__ void g2l16(const void* g, void* l) {
    __builtin_amdgcn_global_load_lds((gptr_t*)g, (lptr_t*)l, 16, 0, 0);
}

// ---------------- fused weight transposes: w_in + w_out -> bf16 T ----------------
__global__ __launch_bounds__(256) void transpose_both(const float* __restrict__ w_in,
                                                      const float* __restrict__ w_out,
                                                      bf16* __restrict__ w_inT,
                                                      bf16* __restrict__ w_outT) {
    __shared__ float tile[32][33];
    int l = blockIdx.x;
    const float* in; bf16* outp; int R, C, bx, by;
    if (l < 7168) { in = w_in;  outp = w_inT;  R = DM_;  C = DPROJ_; bx = l % 224; by = l / 224; }
    else { l -= 7168; in = w_out; outp = w_outT; R = DCAT; C = DM_;   bx = l % 32;  by = l / 32; }
    int c0 = bx * 32, r0 = by * 32;
    int x = threadIdx.x & 31, y = threadIdx.x >> 5;
    for (int i = 0; i < 32; i += 8)
        tile[y + i][x] = in[(size_t)(r0 + y + i) * C + (c0 + x)];
    __syncthreads();
    for (int i = 0; i < 32; i += 8)
        outp[(size_t)(c0 + y + i) * R + (r0 + x)] = (bf16)tile[x][y + i];
}

// ---------------- in-LN + token shift -> xs (bf16) ----------------
__global__ __launch_bounds__(256) void ln_shift(const float* __restrict__ x,
                                                const float* __restrict__ g,
                                                const float* __restrict__ bb,
                                                bf16* __restrict__ xs) {
    int tok = blockIdx.x;
    int b = tok / L_, l = tok % L_;
    const float* row = x + (size_t)tok * DM_;
    float vals[4];
    float s = 0.f, s2 = 0.f;
    for (int i = 0; i < 4; i++) {
        float v = row[threadIdx.x + i * 256];
        vals[i] = v; s += v; s2 += v * v;
    }
    __shared__ float red[2][4];
    for (int o = 32; o; o >>= 1) { s += __shfl_xor(s, o); s2 += __shfl_xor(s2, o); }
    int w = threadIdx.x >> 6;
    if ((threadIdx.x & 63) == 0) { red[0][w] = s; red[1][w] = s2; }
    __syncthreads();
    s  = red[0][0] + red[0][1] + red[0][2] + red[0][3];
    s2 = red[1][0] + red[1][1] + red[1][2] + red[1][3];
    float mean = s * (1.f / DM_);
    float var  = s2 * (1.f / DM_) - mean * mean;
    float rstd = rsqrtf(var + 1e-5f);
    for (int i = 0; i < 4; i++) {
        int c = threadIdx.x + i * 256;
        float y = (vals[i] - mean) * rstd * g[c] + bb[c];
        int shift = (c < 256) ? 1 : ((c >= 896) ? 2 : 0);
        int dl = l + shift;
        if (dl < L_) xs[((size_t)b * L_ + dl) * DM_ + c] = (bf16)y;
        if (l == 0 && shift) {
            xs[((size_t)b * L_ + 0) * DM_ + c] = (bf16)0.f;
            if (shift == 2) xs[((size_t)b * L_ + 1) * DM_ + c] = (bf16)0.f;
        }
    }
}

// ---------------- GEMM1: xs(4096x1024) @ w_inT(7168x1024)^T -> h bf16 ----------------
// 256x128 tile, wave-tile 64x128 (4x8 accs).
__global__ __launch_bounds__(256, 2) void gemm1_k(const bf16* __restrict__ A,
                                                  const bf16* __restrict__ Bt,
                                                  bf16* __restrict__ C) {
    const int K = DM_, N = DPROJ_;
    int lin = blockIdx.x;                 // 896 blocks
    int chunk = lin >> 7, within = lin & 127;
    int m0 = (within >> 3) * 256;
    int n0 = (chunk * 8 + (within & 7)) * 128;
    __shared__ bf16 As[256 * 32];
    __shared__ bf16 Bs[128 * 32];
    int t = threadIdx.x, lane = t & 63, wave = t >> 6;
    int c = lane & 15, quad = lane >> 4;
    int wm = wave * 64;
    floatx4 acc[4][8] = {};
    for (int k0 = 0; k0 < K; k0 += 32) {
        #pragma unroll
        for (int s = 0; s < 4; s++) {
            int f = s * 256 + t;
            int row = f >> 2, kp = (f & 3) * 8;
            g2l16(A + (size_t)(m0 + row) * K + k0 + kp, &As[f * 8]);
        }
        #pragma unroll
        for (int s = 0; s < 2; s++) {
            int f = s * 256 + t;
            int row = f >> 2, kp = (f & 3) * 8;
            g2l16(Bt + (size_t)(n0 + row) * K + k0 + kp, &Bs[f * 8]);
        }
        __syncthreads();
        bf16x8 af[4], bfr[8];
        #pragma unroll
        for (int i = 0; i < 4; i++)
            af[i] = *(const bf16x8*)&As[(wm + i * 16 + c) * 32 + quad * 8];
        #pragma unroll
        for (int j = 0; j < 8; j++)
            bfr[j] = *(const bf16x8*)&Bs[(j * 16 + c) * 32 + quad * 8];
        #pragma unroll
        for (int i = 0; i < 4; i++)
            #pragma unroll
            for (int j = 0; j < 8; j++)
                acc[i][j] = __builtin_amdgcn_mfma_f32_16x16x32_bf16(af[i], bfr[j], acc[i][j], 0, 0, 0);
        __syncthreads();
    }
    #pragma unroll
    for (int i = 0; i < 4; i++)
        #pragma unroll
        for (int j = 0; j < 8; j++)
            #pragma unroll
            for (int r = 0; r < 4; r++) {
                int row = m0 + wm + i * 16 + quad * 4 + r;
                int col = n0 + j * 16 + c;
                C[(size_t)row * N + col] = (bf16)acc[i][j][r];
            }
}

// ---------------- GEMM2 split-K: A2(4096x3072) @ w_outT(1024x3072)^T -> 3 f32 partials ----------------
// Partials are CONTIGUOUS at P: P + kz*NTOK*DM_ (bug fix from R4: host passed
// mismatched base; now one base used by both gemm2_sk and out_ln3).
__global__ __launch_bounds__(256) void gemm2_sk(const bf16* __restrict__ A,
                                                const bf16* __restrict__ Bt,
                                                float* __restrict__ P) {
    const int ldA = DCAT, N = DM_;
    int m0 = blockIdx.x * 128, n0 = blockIdx.y * 128, kz = blockIdx.z;
    const bf16* Ak = A + kz * 1024;
    const bf16* Btk = Bt + kz * 1024;
    float* C = P + (size_t)kz * NTOK * DM_;
    __shared__ bf16 As[128 * 32];
    __shared__ bf16 Bs[128 * 32];
    int t = threadIdx.x, lane = t & 63, wave = t >> 6;
    int c = lane & 15, quad = lane >> 4;
    int wm = (wave >> 1) * 64, wn = (wave & 1) * 64;
    floatx4 acc[4][4] = {};
    for (int k0 = 0; k0 < 1024; k0 += 32) {
        #pragma unroll
        for (int s = 0; s < 2; s++) {
            int f = s * 256 + t;
            int row = f >> 2, kp = (f & 3) * 8;
            g2l16(Ak + (size_t)(m0 + row) * ldA + k0 + kp, &As[f * 8]);
            g2l16(Btk + (size_t)(n0 + row) * ldA + k0 + kp, &Bs[f * 8]);
        }
        __syncthreads();
        bf16x8 af[4], bfr[4];
        #pragma unroll
        for (int i = 0; i < 4; i++)
            af[i] = *(const bf16x8*)&As[(wm + i * 16 + c) * 32 + quad * 8];
        #pragma unroll
        for (int j = 0; j < 4; j++)
            bfr[j] = *(const bf16x8*)&Bs[(wn + j * 16 + c) * 32 + quad * 8];
        #pragma unroll
        for (int i = 0; i < 4; i++)
            #pragma unroll
            for (int j = 0; j < 4; j++)
                acc[i][j] = __builtin_amdgcn_mfma_f32_16x16x32_bf16(af[i], bfr[j], acc[i][j], 0, 0, 0);
        __syncthreads();
    }
    #pragma unroll
    for (int i = 0; i < 4; i++)
        #pragma unroll
        for (int j = 0; j < 4; j++)
            #pragma unroll
            for (int r = 0; r < 4; r++) {
                int row = m0 + wm + i * 16 + quad * 4 + r;
                int col = n0 + wn + j * 16 + c;
                C[(size_t)row * N + col] = acc[i][j][r];
            }
}

// ---------------- mid-LN fused: h -> Qp,Kp,Vn packed [b,h,L,64] + gated A2 ----------------
__global__ __launch_bounds__(256) void mid_ln_fused(const bf16* __restrict__ h,
                                                    const float* __restrict__ g,
                                                    const float* __restrict__ bb,
                                                    bf16* __restrict__ Qp,
                                                    bf16* __restrict__ Kp,
                                                    bf16* __restrict__ Vn,
                                                    bf16* __restrict__ A2) {
    int tok = blockIdx.x;
    int b = tok >> 11, l = tok & 2047;
    size_t base = (size_t)tok * DPROJ_;
    int t = threadIdx.x;
    float v[28];
    float s = 0.f, s2 = 0.f;
    for (int i = 0; i < 28; i++) {
        v[i] = (float)h[base + t + i * 256];
        s += v[i]; s2 += v[i] * v[i];
    }
    __shared__ float red[2][4];
    for (int o = 32; o; o >>= 1) { s += __shfl_xor(s, o); s2 += __shfl_xor(s2, o); }
    int w = t >> 6;
    if ((t & 63) == 0) { red[0][w] = s; red[1][w] = s2; }
    __syncthreads();
    s  = red[0][0] + red[0][1] + red[0][2] + red[0][3];
    s2 = red[1][0] + red[1][1] + red[1][2] + red[1][3];
    float mean = s * (1.f / DPROJ_);
    float var  = s2 * (1.f / DPROJ_) - mean * mean;
    float rstd = rsqrtf(var + 1e-5f);
    #pragma unroll
    for (int i = 0; i < 28; i++) {
        int c = t + i * 256;
        v[i] = (v[i] - mean) * rstd * g[c] + bb[c];
    }
    #pragma unroll
    for (int i = 0; i < 12; i++) {
        int c = t + i * 256;
        int sec = c >> 10;
        int cc = c & 1023;
        int hh = cc >> 6, d = cc & 63;
        size_t idx = (((size_t)b * HEADS_ + hh) * L_ + l) * DH_ + d;
        bf16* dst = (sec == 0) ? Qp : (sec == 1) ? Kp : Vn;
        dst[idx] = (bf16)v[i];
    }
    #pragma unroll
    for (int i = 12; i < 20; i++) {
        int c = t + i * 256;
        A2[(size_t)tok * DCAT + DM_ + (c - 3 * DM_)] = (bf16)(v[i] * v[i + 8]);
    }
}

// ---------------- Vn [b,h,L,64] -> Vt [b,h,64,L] ----------------
__global__ __launch_bounds__(256) void vt_pack(const bf16* __restrict__ Vn,
                                               bf16* __restrict__ Vt) {
    __shared__ bf16 tile[32][33];
    int bh = blockIdx.z;
    const bf16* in = Vn + (size_t)bh * L_ * DH_;
    bf16* out = Vt + (size_t)bh * DH_ * L_;
    int l0 = blockIdx.x * 32, d0 = blockIdx.y * 32;
    int x = threadIdx.x & 31, y = threadIdx.x >> 5;
    for (int i = 0; i < 32; i += 8)
        tile[y + i][x] = in[(size_t)(l0 + y + i) * DH_ + d0 + x];
    __syncthreads();
    for (int i = 0; i < 32; i += 8)
        out[(size_t)(d0 + y + i) * L_ + l0 + x] = tile[x][y + i];
}

// ---------------- flash attention v3 ----------------
__global__ __launch_bounds__(256, 4) void attn3(const bf16* __restrict__ Qp,
                                                const bf16* __restrict__ Kp,
                                                const bf16* __restrict__ Vt,
                                                const float* __restrict__ slopes,
                                                bf16* __restrict__ A2) {
    int hd = blockIdx.y, b = blockIdx.z;
    int lin = blockIdx.x + 32 * blockIdx.y + 512 * blockIdx.z;
    int xr = blockIdx.x;
    int qt = ((lin >> 8) & 1) ? (31 - xr) : xr;
    int q0 = qt * 64;
    int t = threadIdx.x, lane = t & 63, wave = t >> 6;
    int quad = lane >> 4, c = lane & 15;
    __shared__ bf16 Ks[2 * 64 * 32];
    __shared__ bf16 Vs[2 * 64 * 32];
    __shared__ bf16 Ps[4][16 * 72];
    int bh = b * HEADS_ + hd;
    const bf16* Qb = Qp + (size_t)bh * L_ * DH_;
    const bf16* Kb = Kp + (size_t)bh * L_ * DH_;
    const bf16* Vb = Vt + (size_t)bh * DH_ * L_;
    const float LOG2E = 1.44269504f;
    float slopeL2 = slopes[hd] * LOG2E;
    const float qscale = 0.125f * LOG2E;

    bf16x8 qf[2];
    int qrow = q0 + wave * 16 + c;
    qf[0] = *(const bf16x8*)(Qb + (size_t)qrow * DH_ + quad * 8);
    qf[1] = *(const bf16x8*)(Qb + (size_t)qrow * DH_ + 32 + quad * 8);
    floatx4 accO[4] = {};
    float m_r[4], l_r[4];
    #pragma unroll
    for (int r = 0; r < 4; r++) { m_r[r] = -1e30f; l_r[r] = 0.f; }

    int row = t >> 2, kp = (t & 3) * 8;
    for (int j0 = 0; j0 <= q0; j0 += 64) {
        #pragma unroll
        for (int s = 0; s < 2; s++) {
            g2l16(Kb + (size_t)(j0 + row) * DH_ + s * 32 + kp, &Ks[(s * 256 + t) * 8]);
            g2l16(Vb + (size_t)row * L_ + j0 + s * 32 + kp, &Vs[(s * 256 + t) * 8]);
        }
        __syncthreads();

        float sv[4][4];
        bool diag = (j0 == q0);
        #pragma unroll
        for (int nt = 0; nt < 4; nt++) {
            floatx4 sacc = {};
            bf16x8 kf0 = *(const bf16x8*)&Ks[(nt * 16 + c) * 32 + quad * 8];
            bf16x8 kf1 = *(const bf16x8*)&Ks[2048 + (nt * 16 + c) * 32 + quad * 8];
            sacc = __builtin_amdgcn_mfma_f32_16x16x32_bf16(qf[0], kf0, sacc, 0, 0, 0);
            sacc = __builtin_amdgcn_mfma_f32_16x16x32_bf16(qf[1], kf1, sacc, 0, 0, 0);
            int j = j0 + nt * 16 + c;
            float al = slopeL2 * (float)j;
            #pragma unroll
            for (int r = 0; r < 4; r++) {
                float s2v = sacc[r] * qscale + al;
                if (diag) {
                    int i_row = q0 + wave * 16 + quad * 4 + r;
                    s2v = (j <= i_row) ? s2v : -1e30f;
                }
                sv[nt][r] = s2v;
            }
        }
        float alpha[4];
        #pragma unroll
        for (int r = 0; r < 4; r++) {
            float mt = fmaxf(fmaxf(sv[0][r], sv[1][r]), fmaxf(sv[2][r], sv[3][r]));
            mt = fmaxf(mt, __shfl_xor(mt, 1));
            mt = fmaxf(mt, __shfl_xor(mt, 2));
            mt = fmaxf(mt, __shfl_xor(mt, 4));
            mt = fmaxf(mt, __shfl_xor(mt, 8));
            float mnew = fmaxf(m_r[r], mt);
            alpha[r] = exp2f(m_r[r] - mnew);
            float ps = 0.f;
            #pragma unroll
            for (int nt = 0; nt < 4; nt++) {
                float p = exp2f(sv[nt][r] - mnew);
                sv[nt][r] = p;
                ps += p;
            }
            ps += __shfl_xor(ps, 1);
            ps += __shfl_xor(ps, 2);
            ps += __shfl_xor(ps, 4);
            ps += __shfl_xor(ps, 8);
            l_r[r] = l_r[r] * alpha[r] + ps;
            m_r[r] = mnew;
        }
        bf16* pw = &Ps[wave][0];
        #pragma unroll
        for (int nt = 0; nt < 4; nt++)
            #pragma unroll
            for (int r = 0; r < 4; r++)
                pw[(quad * 4 + r) * 72 + nt * 16 + c] = (bf16)sv[nt][r];
        #pragma unroll
        for (int nt = 0; nt < 4; nt++)
            #pragma unroll
            for (int r = 0; r < 4; r++)
                accO[nt][r] *= alpha[r];
        bf16x8 pf0 = *(const bf16x8*)&pw[c * 72 + quad * 8];
        bf16x8 pf1 = *(const bf16x8*)&pw[c * 72 + 32 + quad * 8];
        #pragma unroll
        for (int nt = 0; nt < 4; nt++) {
            bf16x8 vf0 = *(const bf16x8*)&Vs[(nt * 16 + c) * 32 + quad * 8];
            bf16x8 vf1 = *(const bf16x8*)&Vs[2048 + (nt * 16 + c) * 32 + quad * 8];
            accO[nt] = __builtin_amdgcn_mfma_f32_16x16x32_bf16(pf0, vf0, accO[nt], 0, 0, 0);
            accO[nt] = __builtin_amdgcn_mfma_f32_16x16x32_bf16(pf1, vf1, accO[nt], 0, 0, 0);
        }
        __syncthreads();
    }
    #pragma unroll
    for (int r = 0; r < 4; r++) {
        float inv = 1.f / l_r[r];
        size_t orow = (size_t)b * L_ + q0 + wave * 16 + quad * 4 + r;
        #pragma unroll
        for (int nt = 0; nt < 4; nt++)
            A2[orow * DCAT + hd * DH_ + nt * 16 + c] = (bf16)(accO[nt][r] * inv);
    }
}

// ---------------- out-LN over sum of 3 contiguous split-K partials ----------------
__global__ __launch_bounds__(256) void out_ln3(const float* __restrict__ P,
                                               const float* __restrict__ g,
                                               const float* __restrict__ bb,
                                               float* __restrict__ out) {
    size_t base = (size_t)blockIdx.x * DM_;
    const size_t stride = (size_t)NTOK * DM_;
    float v[4];
    float s = 0.f, s2 = 0.f;
    for (int i = 0; i < 4; i++) {
        size_t idx = base + threadIdx.x + i * 256;
        v[i] = P[idx] + P[idx + stride] + P[idx + 2 * stride];
        s += v[i]; s2 += v[i] * v[i];
    }
    __shared__ float red[2][4];
    for (int o = 32; o; o >>= 1) { s += __shfl_xor(s, o); s2 += __shfl_xor(s2, o); }
    int w = threadIdx.x >> 6;
    if ((threadIdx.x & 63) == 0) { red[0][w] = s; red[1][w] = s2; }
    __syncthreads();
    s  = red[0][0] + red[0][1] + red[0][2] + red[0][3];
    s2 = red[1][0] + red[1][1] + red[1][2] + red[1][3];
    float mean = s * (1.f / DM_);
    float var  = s2 * (1.f / DM_) - mean * mean;
    float rstd = rsqrtf(var + 1e-5f);
    for (int i = 0; i < 4; i++) {
        int c = threadIdx.x + i * 256;
        out[base + c] = (v[i] - mean) * rstd * g[c] + bb[c];
    }
}

extern "C" void kernel_launch(void* const* d_in, const int* in_sizes, int n_in,
                              void* d_out, int out_size, void* d_ws, size_t ws_size,
                              hipStream_t stream) {
    const float* x     = (const float*)d_in[0];
    const float* in_g  = (const float*)d_in[1];
    const float* in_b  = (const float*)d_in[2];
    const float* mid_g = (const float*)d_in[3];
    const float* mid_b = (const float*)d_in[4];
    const float* out_g = (const float*)d_in[5];
    const float* out_b = (const float*)d_in[6];
    const float* w_in  = (const float*)d_in[7];
    const float* w_out = (const float*)d_in[8];
    const float* slopes = (const float*)d_in[9];
    float* out = (float*)d_out;

    char* ws = (char*)d_ws;
    size_t off = 0;
    auto alloc = [&](size_t n) { char* p = ws + off; off += (n + 255) & ~(size_t)255; return p; };
    bf16* w_inT  = (bf16*)alloc((size_t)DPROJ_ * DM_ * 2);   // 14.7 MB
    bf16* w_outT = (bf16*)alloc((size_t)DM_ * DCAT * 2);     // 6.3 MB
    bf16* xs     = (bf16*)alloc((size_t)NTOK * DM_ * 2);     // 8.4 MB (reused as Vt)
    bf16* h      = (bf16*)alloc((size_t)NTOK * DPROJ_ * 2);  // 58.7 MB (reused: 3 contig f32 partials = 50.3 MB)
    bf16* A2     = (bf16*)alloc((size_t)NTOK * DCAT * 2);    // 25.2 MB
    bf16* Qp     = (bf16*)alloc((size_t)NTOK * DM_ * 2);     // 8.4 MB
    bf16* Kp     = (bf16*)alloc((size_t)NTOK * DM_ * 2);     // 8.4 MB
    bf16* Vn     = (bf16*)alloc((size_t)NTOK * DM_ * 2);     // 8.4 MB
    bf16* Vt = xs;            // xs dead after gemm1
    float* P = (float*)h;     // h dead after mid_ln_fused; gemm2 runs after attn3

    hipLaunchKernelGGL(transpose_both, dim3(7168 + 3072), dim3(256), 0, stream,
                       w_in, w_out, w_inT, w_outT);
    hipLaunchKernelGGL(ln_shift, dim3(NTOK), dim3(256), 0, stream, x, in_g, in_b, xs);
    hipLaunchKernelGGL(gemm1_k, dim3(896), dim3(256), 0, stream, xs, w_inT, h);
    hipLaunchKernelGGL(mid_ln_fused, dim3(NTOK), dim3(256), 0, stream, h, mid_g, mid_b,
                       Qp, Kp, Vn, A2);
    hipLaunchKernelGGL(vt_pack, dim3(L_ / 32, DH_ / 32, B_ * HEADS_), dim3(256), 0, stream, Vn, Vt);
    hipLaunchKernelGGL(attn3, dim3(32, HEADS_, B_), dim3(256), 0, stream, Qp, Kp, Vt, slopes, A2);
    hipLaunchKernelGGL(gemm2_sk, dim3(NTOK / 128, DM_ / 128, 3), dim3(256), 0, stream,
                       A2, w_outT, P);
    hipLaunchKernelGGL(out_ln3, dim3(NTOK), dim3(256), 0, stream, P, out_g, out_b, out);
}

// Round 6
// 332.562 us; speedup vs baseline: 1.5883x; 1.0737x over previous
//
#include <hip/hip_runtime.h>

#define B_ 2
#define L_ 2048
#define HEADS_ 16
#define DH_ 64
#define DM_ 1024
#define DBI_ 2048
#define DPROJ_ 7168
#define NTOK (B_*L_)      // 4096
#define DCAT (DM_ + DBI_) // 3072

typedef __bf16 bf16;
typedef __attribute__((ext_vector_type(8))) __bf16 bf16x8;
typedef __attribute__((ext_vector_type(4))) float floatx4;

typedef __attribute__((address_space(1))) const void gptr_t;
typedef __attribute__((address_space(3))) void lptr_t;

__device__ __forceinline__ void g2l16(const void* g, void* l) {
    __builtin_amdgcn_global_load_lds((gptr_t*)g, (lptr_t*)l, 16, 0, 0);
}

// ---------------- fused weight transposes: w_in + w_out -> bf16 T ----------------
__global__ __launch_bounds__(256) void transpose_both(const float* __restrict__ w_in,
                                                      const float* __restrict__ w_out,
                                                      bf16* __restrict__ w_inT,
                                                      bf16* __restrict__ w_outT) {
    __shared__ float tile[32][33];
    int l = blockIdx.x;
    const float* in; bf16* outp; int R, C, bx, by;
    if (l < 7168) { in = w_in;  outp = w_inT;  R = DM_;  C = DPROJ_; bx = l % 224; by = l / 224; }
    else { l -= 7168; in = w_out; outp = w_outT; R = DCAT; C = DM_;   bx = l % 32;  by = l / 32; }
    int c0 = bx * 32, r0 = by * 32;
    int x = threadIdx.x & 31, y = threadIdx.x >> 5;
    for (int i = 0; i < 32; i += 8)
        tile[y + i][x] = in[(size_t)(r0 + y + i) * C + (c0 + x)];
    __syncthreads();
    for (int i = 0; i < 32; i += 8)
        outp[(size_t)(c0 + y + i) * R + (r0 + x)] = (bf16)tile[x][y + i];
}

// ---------------- in-LN + token shift -> xs (bf16) ----------------
__global__ __launch_bounds__(256) void ln_shift(const float* __restrict__ x,
                                                const float* __restrict__ g,
                                                const float* __restrict__ bb,
                                                bf16* __restrict__ xs) {
    int tok = blockIdx.x;
    int b = tok / L_, l = tok % L_;
    const float* row = x + (size_t)tok * DM_;
    float vals[4];
    float s = 0.f, s2 = 0.f;
    for (int i = 0; i < 4; i++) {
        float v = row[threadIdx.x + i * 256];
        vals[i] = v; s += v; s2 += v * v;
    }
    __shared__ float red[2][4];
    for (int o = 32; o; o >>= 1) { s += __shfl_xor(s, o); s2 += __shfl_xor(s2, o); }
    int w = threadIdx.x >> 6;
    if ((threadIdx.x & 63) == 0) { red[0][w] = s; red[1][w] = s2; }
    __syncthreads();
    s  = red[0][0] + red[0][1] + red[0][2] + red[0][3];
    s2 = red[1][0] + red[1][1] + red[1][2] + red[1][3];
    float mean = s * (1.f / DM_);
    float var  = s2 * (1.f / DM_) - mean * mean;
    float rstd = rsqrtf(var + 1e-5f);
    for (int i = 0; i < 4; i++) {
        int c = threadIdx.x + i * 256;
        float y = (vals[i] - mean) * rstd * g[c] + bb[c];
        int shift = (c < 256) ? 1 : ((c >= 896) ? 2 : 0);
        int dl = l + shift;
        if (dl < L_) xs[((size_t)b * L_ + dl) * DM_ + c] = (bf16)y;
        if (l == 0 && shift) {
            xs[((size_t)b * L_ + 0) * DM_ + c] = (bf16)0.f;
            if (shift == 2) xs[((size_t)b * L_ + 1) * DM_ + c] = (bf16)0.f;
        }
    }
}

// ---------------- GEMM1: xs(4096x1024) @ w_inT(7168x1024)^T -> h bf16 ----------------
__global__ __launch_bounds__(256, 2) void gemm1_k(const bf16* __restrict__ A,
                                                  const bf16* __restrict__ Bt,
                                                  bf16* __restrict__ C) {
    const int K = DM_, N = DPROJ_;
    int lin = blockIdx.x;                 // 896 blocks
    int chunk = lin >> 7, within = lin & 127;
    int m0 = (within >> 3) * 256;
    int n0 = (chunk * 8 + (within & 7)) * 128;
    __shared__ bf16 As[256 * 32];
    __shared__ bf16 Bs[128 * 32];
    int t = threadIdx.x, lane = t & 63, wave = t >> 6;
    int c = lane & 15, quad = lane >> 4;
    int wm = wave * 64;
    floatx4 acc[4][8] = {};
    for (int k0 = 0; k0 < K; k0 += 32) {
        #pragma unroll
        for (int s = 0; s < 4; s++) {
            int f = s * 256 + t;
            int row = f >> 2, kp = (f & 3) * 8;
            g2l16(A + (size_t)(m0 + row) * K + k0 + kp, &As[f * 8]);
        }
        #pragma unroll
        for (int s = 0; s < 2; s++) {
            int f = s * 256 + t;
            int row = f >> 2, kp = (f & 3) * 8;
            g2l16(Bt + (size_t)(n0 + row) * K + k0 + kp, &Bs[f * 8]);
        }
        __syncthreads();
        bf16x8 af[4], bfr[8];
        #pragma unroll
        for (int i = 0; i < 4; i++)
            af[i] = *(const bf16x8*)&As[(wm + i * 16 + c) * 32 + quad * 8];
        #pragma unroll
        for (int j = 0; j < 8; j++)
            bfr[j] = *(const bf16x8*)&Bs[(j * 16 + c) * 32 + quad * 8];
        #pragma unroll
        for (int i = 0; i < 4; i++)
            #pragma unroll
            for (int j = 0; j < 8; j++)
                acc[i][j] = __builtin_amdgcn_mfma_f32_16x16x32_bf16(af[i], bfr[j], acc[i][j], 0, 0, 0);
        __syncthreads();
    }
    #pragma unroll
    for (int i = 0; i < 4; i++)
        #pragma unroll
        for (int j = 0; j < 8; j++)
            #pragma unroll
            for (int r = 0; r < 4; r++) {
                int row = m0 + wm + i * 16 + quad * 4 + r;
                int col = n0 + j * 16 + c;
                C[(size_t)row * N + col] = (bf16)acc[i][j][r];
            }
}

// ---------------- GEMM2 split-K: contiguous partials at P + kz*NTOK*DM_ ----------------
__global__ __launch_bounds__(256) void gemm2_sk(const bf16* __restrict__ A,
                                                const bf16* __restrict__ Bt,
                                                float* __restrict__ P) {
    const int ldA = DCAT, N = DM_;
    int m0 = blockIdx.x * 128, n0 = blockIdx.y * 128, kz = blockIdx.z;
    const bf16* Ak = A + kz * 1024;
    const bf16* Btk = Bt + kz * 1024;
    float* C = P + (size_t)kz * NTOK * DM_;
    __shared__ bf16 As[128 * 32];
    __shared__ bf16 Bs[128 * 32];
    int t = threadIdx.x, lane = t & 63, wave = t >> 6;
    int c = lane & 15, quad = lane >> 4;
    int wm = (wave >> 1) * 64, wn = (wave & 1) * 64;
    floatx4 acc[4][4] = {};
    for (int k0 = 0; k0 < 1024; k0 += 32) {
        #pragma unroll
        for (int s = 0; s < 2; s++) {
            int f = s * 256 + t;
            int row = f >> 2, kp = (f & 3) * 8;
            g2l16(Ak + (size_t)(m0 + row) * ldA + k0 + kp, &As[f * 8]);
            g2l16(Btk + (size_t)(n0 + row) * ldA + k0 + kp, &Bs[f * 8]);
        }
        __syncthreads();
        bf16x8 af[4], bfr[4];
        #pragma unroll
        for (int i = 0; i < 4; i++)
            af[i] = *(const bf16x8*)&As[(wm + i * 16 + c) * 32 + quad * 8];
        #pragma unroll
        for (int j = 0; j < 4; j++)
            bfr[j] = *(const bf16x8*)&Bs[(wn + j * 16 + c) * 32 + quad * 8];
        #pragma unroll
        for (int i = 0; i < 4; i++)
            #pragma unroll
            for (int j = 0; j < 4; j++)
                acc[i][j] = __builtin_amdgcn_mfma_f32_16x16x32_bf16(af[i], bfr[j], acc[i][j], 0, 0, 0);
        __syncthreads();
    }
    #pragma unroll
    for (int i = 0; i < 4; i++)
        #pragma unroll
        for (int j = 0; j < 4; j++)
            #pragma unroll
            for (int r = 0; r < 4; r++) {
                int row = m0 + wm + i * 16 + quad * 4 + r;
                int col = n0 + wn + j * 16 + c;
                C[(size_t)row * N + col] = acc[i][j][r];
            }
}

// ---------------- mid-LN fused: h -> Qp,Kp,Vn packed [b,h,L,64] + gated A2 ----------------
__global__ __launch_bounds__(256) void mid_ln_fused(const bf16* __restrict__ h,
                                                    const float* __restrict__ g,
                                                    const float* __restrict__ bb,
                                                    bf16* __restrict__ Qp,
                                                    bf16* __restrict__ Kp,
                                                    bf16* __restrict__ Vn,
                                                    bf16* __restrict__ A2) {
    int tok = blockIdx.x;
    int b = tok >> 11, l = tok & 2047;
    size_t base = (size_t)tok * DPROJ_;
    int t = threadIdx.x;
    float v[28];
    float s = 0.f, s2 = 0.f;
    for (int i = 0; i < 28; i++) {
        v[i] = (float)h[base + t + i * 256];
        s += v[i]; s2 += v[i] * v[i];
    }
    __shared__ float red[2][4];
    for (int o = 32; o; o >>= 1) { s += __shfl_xor(s, o); s2 += __shfl_xor(s2, o); }
    int w = t >> 6;
    if ((t & 63) == 0) { red[0][w] = s; red[1][w] = s2; }
    __syncthreads();
    s  = red[0][0] + red[0][1] + red[0][2] + red[0][3];
    s2 = red[1][0] + red[1][1] + red[1][2] + red[1][3];
    float mean = s * (1.f / DPROJ_);
    float var  = s2 * (1.f / DPROJ_) - mean * mean;
    float rstd = rsqrtf(var + 1e-5f);
    #pragma unroll
    for (int i = 0; i < 28; i++) {
        int c = t + i * 256;
        v[i] = (v[i] - mean) * rstd * g[c] + bb[c];
    }
    #pragma unroll
    for (int i = 0; i < 12; i++) {
        int c = t + i * 256;
        int sec = c >> 10;
        int cc = c & 1023;
        int hh = cc >> 6, d = cc & 63;
        size_t idx = (((size_t)b * HEADS_ + hh) * L_ + l) * DH_ + d;
        bf16* dst = (sec == 0) ? Qp : (sec == 1) ? Kp : Vn;
        dst[idx] = (bf16)v[i];
    }
    #pragma unroll
    for (int i = 12; i < 20; i++) {
        int c = t + i * 256;
        A2[(size_t)tok * DCAT + DM_ + (c - 3 * DM_)] = (bf16)(v[i] * v[i + 8]);
    }
}

// ---------------- Vn [b,h,L,64] -> Vt [b,h,64,L] ----------------
__global__ __launch_bounds__(256) void vt_pack(const bf16* __restrict__ Vn,
                                               bf16* __restrict__ Vt) {
    __shared__ bf16 tile[32][33];
    int bh = blockIdx.z;
    const bf16* in = Vn + (size_t)bh * L_ * DH_;
    bf16* out = Vt + (size_t)bh * DH_ * L_;
    int l0 = blockIdx.x * 32, d0 = blockIdx.y * 32;
    int x = threadIdx.x & 31, y = threadIdx.x >> 5;
    for (int i = 0; i < 32; i += 8)
        tile[y + i][x] = in[(size_t)(l0 + y + i) * DH_ + d0 + x];
    __syncthreads();
    for (int i = 0; i < 32; i += 8)
        out[(size_t)(d0 + y + i) * L_ + l0 + x] = tile[x][y + i];
}

// ---------------- flash attention v4: fixed-max softmax ----------------
// m_est(i) = slopeL2*i + 20 is a static row bound (causal+ALiBi): no max
// reduction, no alpha rescale, l = plain sum (per-thread partials, one
// 4-shfl reduce at end). p,l,accO all carry the same 2^-20-ish scaling.
__global__ __launch_bounds__(256, 4) void attn4(const bf16* __restrict__ Qp,
                                                const bf16* __restrict__ Kp,
                                                const bf16* __restrict__ Vt,
                                                const float* __restrict__ slopes,
                                                bf16* __restrict__ A2) {
    int hd = blockIdx.y, b = blockIdx.z;
    int lin = blockIdx.x + 32 * blockIdx.y + 512 * blockIdx.z;
    int xr = blockIdx.x;
    int qt = ((lin >> 8) & 1) ? (31 - xr) : xr;
    int q0 = qt * 64;
    int t = threadIdx.x, lane = t & 63, wave = t >> 6;
    int quad = lane >> 4, c = lane & 15;
    __shared__ bf16 Ks[2 * 64 * 32];
    __shared__ bf16 Vs[2 * 64 * 32];
    __shared__ bf16 Ps[4][16 * 72];
    int bh = b * HEADS_ + hd;
    const bf16* Qb = Qp + (size_t)bh * L_ * DH_;
    const bf16* Kb = Kp + (size_t)bh * L_ * DH_;
    const bf16* Vb = Vt + (size_t)bh * DH_ * L_;
    const float LOG2E = 1.44269504f;
    float slopeL2 = slopes[hd] * LOG2E;
    const float qscale = 0.125f * LOG2E;

    bf16x8 qf[2];
    int qrow = q0 + wave * 16 + c;
    qf[0] = *(const bf16x8*)(Qb + (size_t)qrow * DH_ + quad * 8);
    qf[1] = *(const bf16x8*)(Qb + (size_t)qrow * DH_ + 32 + quad * 8);
    floatx4 accO[4] = {};
    float lsum[4];
    float mrow[4];
    int i_row0 = q0 + wave * 16 + quad * 4;
    #pragma unroll
    for (int r = 0; r < 4; r++) {
        lsum[r] = 0.f;
        mrow[r] = slopeL2 * (float)(i_row0 + r) + 20.0f;
    }

    int row = t >> 2, kp = (t & 3) * 8;
    bf16* pw = &Ps[wave][0];
    bf16* pwr = pw + (quad * 4) * 72 + c;   // base for immediate-offset writes
    for (int j0 = 0; j0 <= q0; j0 += 64) {
        #pragma unroll
        for (int s = 0; s < 2; s++) {
            g2l16(Kb + (size_t)(j0 + row) * DH_ + s * 32 + kp, &Ks[(s * 256 + t) * 8]);
            g2l16(Vb + (size_t)row * L_ + j0 + s * 32 + kp, &Vs[(s * 256 + t) * 8]);
        }
        __syncthreads();

        bool diag = (j0 == q0);
        #pragma unroll
        for (int nt = 0; nt < 4; nt++) {
            floatx4 sacc = {};
            bf16x8 kf0 = *(const bf16x8*)&Ks[(nt * 16 + c) * 32 + quad * 8];
            bf16x8 kf1 = *(const bf16x8*)&Ks[2048 + (nt * 16 + c) * 32 + quad * 8];
            sacc = __builtin_amdgcn_mfma_f32_16x16x32_bf16(qf[0], kf0, sacc, 0, 0, 0);
            sacc = __builtin_amdgcn_mfma_f32_16x16x32_bf16(qf[1], kf1, sacc, 0, 0, 0);
            int j = j0 + nt * 16 + c;
            float aj = slopeL2 * (float)j;
            #pragma unroll
            for (int r = 0; r < 4; r++) {
                float p = exp2f(fmaf(sacc[r], qscale, aj) - mrow[r]);
                if (diag) p = (j <= i_row0 + r) ? p : 0.f;
                lsum[r] += p;
                pwr[r * 72 + nt * 16] = (bf16)p;
            }
        }
        bf16x8 pf0 = *(const bf16x8*)&pw[c * 72 + quad * 8];
        bf16x8 pf1 = *(const bf16x8*)&pw[c * 72 + 32 + quad * 8];
        #pragma unroll
        for (int nt = 0; nt < 4; nt++) {
            bf16x8 vf0 = *(const bf16x8*)&Vs[(nt * 16 + c) * 32 + quad * 8];
            bf16x8 vf1 = *(const bf16x8*)&Vs[2048 + (nt * 16 + c) * 32 + quad * 8];
            accO[nt] = __builtin_amdgcn_mfma_f32_16x16x32_bf16(pf0, vf0, accO[nt], 0, 0, 0);
            accO[nt] = __builtin_amdgcn_mfma_f32_16x16x32_bf16(pf1, vf1, accO[nt], 0, 0, 0);
        }
        __syncthreads();
    }
    // reduce l over the 16 c-lanes (once)
    #pragma unroll
    for (int r = 0; r < 4; r++) {
        float l = lsum[r];
        l += __shfl_xor(l, 1);
        l += __shfl_xor(l, 2);
        l += __shfl_xor(l, 4);
        l += __shfl_xor(l, 8);
        lsum[r] = 1.f / l;
    }
    #pragma unroll
    for (int r = 0; r < 4; r++) {
        size_t orow = (size_t)b * L_ + q0 + wave * 16 + quad * 4 + r;
        #pragma unroll
        for (int nt = 0; nt < 4; nt++)
            A2[orow * DCAT + hd * DH_ + nt * 16 + c] = (bf16)(accO[nt][r] * lsum[r]);
    }
}

// ---------------- out-LN over sum of 3 contiguous split-K partials ----------------
__global__ __launch_bounds__(256) void out_ln3(const float* __restrict__ P,
                                               const float* __restrict__ g,
                                               const float* __restrict__ bb,
                                               float* __restrict__ out) {
    size_t base = (size_t)blockIdx.x * DM_;
    const size_t stride = (size_t)NTOK * DM_;
    float v[4];
    float s = 0.f, s2 = 0.f;
    for (int i = 0; i < 4; i++) {
        size_t idx = base + threadIdx.x + i * 256;
        v[i] = P[idx] + P[idx + stride] + P[idx + 2 * stride];
        s += v[i]; s2 += v[i] * v[i];
    }
    __shared__ float red[2][4];
    for (int o = 32; o; o >>= 1) { s += __shfl_xor(s, o); s2 += __shfl_xor(s2, o); }
    int w = threadIdx.x >> 6;
    if ((threadIdx.x & 63) == 0) { red[0][w] = s; red[1][w] = s2; }
    __syncthreads();
    s  = red[0][0] + red[0][1] + red[0][2] + red[0][3];
    s2 = red[1][0] + red[1][1] + red[1][2] + red[1][3];
    float mean = s * (1.f / DM_);
    float var  = s2 * (1.f / DM_) - mean * mean;
    float rstd = rsqrtf(var + 1e-5f);
    for (int i = 0; i < 4; i++) {
        int c = threadIdx.x + i * 256;
        out[base + c] = (v[i] - mean) * rstd * g[c] + bb[c];
    }
}

extern "C" void kernel_launch(void* const* d_in, const int* in_sizes, int n_in,
                              void* d_out, int out_size, void* d_ws, size_t ws_size,
                              hipStream_t stream) {
    const float* x     = (const float*)d_in[0];
    const float* in_g  = (const float*)d_in[1];
    const float* in_b  = (const float*)d_in[2];
    const float* mid_g = (const float*)d_in[3];
    const float* mid_b = (const float*)d_in[4];
    const float* out_g = (const float*)d_in[5];
    const float* out_b = (const float*)d_in[6];
    const float* w_in  = (const float*)d_in[7];
    const float* w_out = (const float*)d_in[8];
    const float* slopes = (const float*)d_in[9];
    float* out = (float*)d_out;

    char* ws = (char*)d_ws;
    size_t off = 0;
    auto alloc = [&](size_t n) { char* p = ws + off; off += (n + 255) & ~(size_t)255; return p; };
    bf16* w_inT  = (bf16*)alloc((size_t)DPROJ_ * DM_ * 2);   // 14.7 MB
    bf16* w_outT = (bf16*)alloc((size_t)DM_ * DCAT * 2);     // 6.3 MB
    bf16* xs     = (bf16*)alloc((size_t)NTOK * DM_ * 2);     // 8.4 MB (reused as Vt)
    bf16* h      = (bf16*)alloc((size_t)NTOK * DPROJ_ * 2);  // 58.7 MB (reused: 3 contig f32 partials)
    bf16* A2     = (bf16*)alloc((size_t)NTOK * DCAT * 2);    // 25.2 MB
    bf16* Qp     = (bf16*)alloc((size_t)NTOK * DM_ * 2);     // 8.4 MB
    bf16* Kp     = (bf16*)alloc((size_t)NTOK * DM_ * 2);     // 8.4 MB
    bf16* Vn     = (bf16*)alloc((size_t)NTOK * DM_ * 2);     // 8.4 MB
    bf16* Vt = xs;            // xs dead after gemm1
    float* P = (float*)h;     // h dead after mid_ln_fused; gemm2 runs after attn

    hipLaunchKernelGGL(transpose_both, dim3(7168 + 3072), dim3(256), 0, stream,
                       w_in, w_out, w_inT, w_outT);
    hipLaunchKernelGGL(ln_shift, dim3(NTOK), dim3(256), 0, stream, x, in_g, in_b, xs);
    hipLaunchKernelGGL(gemm1_k, dim3(896), dim3(256), 0, stream, xs, w_inT, h);
    hipLaunchKernelGGL(mid_ln_fused, dim3(NTOK), dim3(256), 0, stream, h, mid_g, mid_b,
                       Qp, Kp, Vn, A2);
    hipLaunchKernelGGL(vt_pack, dim3(L_ / 32, DH_ / 32, B_ * HEADS_), dim3(256), 0, stream, Vn, Vt);
    hipLaunchKernelGGL(attn4, dim3(32, HEADS_, B_), dim3(256), 0, stream, Qp, Kp, Vt, slopes, A2);
    hipLaunchKernelGGL(gemm2_sk, dim3(NTOK / 128, DM_ / 128, 3), dim3(256), 0, stream,
                       A2, w_outT, P);
    hipLaunchKernelGGL(out_ln3, dim3(NTOK), dim3(256), 0, stream, P, out_g, out_b, out);
}

// Round 7
// 317.301 us; speedup vs baseline: 1.6647x; 1.0481x over previous
//
#include <hip/hip_runtime.h>

#define B_ 2
#define L_ 2048
#define HEADS_ 16
#define DH_ 64
#define DM_ 1024
#define DBI_ 2048
#define DPROJ_ 7168
#define NTOK (B_*L_)      // 4096
#define DCAT (DM_ + DBI_) // 3072

typedef __bf16 bf16;
typedef __attribute__((ext_vector_type(8))) __bf16 bf16x8;
typedef __attribute__((ext_vector_type(4))) float floatx4;

typedef __attribute__((address_space(1))) const void gptr_t;
typedef __attribute__((address_space(3))) void lptr_t;

__device__ __forceinline__ void g2l16(const void* g, void* l) {
    __builtin_amdgcn_global_load_lds((gptr_t*)g, (lptr_t*)l, 16, 0, 0);
}

// ---------------- fused weight transposes: w_in + w_out -> bf16 T ----------------
__global__ __launch_bounds__(256) void transpose_both(const float* __restrict__ w_in,
                                                      const float* __restrict__ w_out,
                                                      bf16* __restrict__ w_inT,
                                                      bf16* __restrict__ w_outT) {
    __shared__ float tile[32][33];
    int l = blockIdx.x;
    const float* in; bf16* outp; int R, C, bx, by;
    if (l < 7168) { in = w_in;  outp = w_inT;  R = DM_;  C = DPROJ_; bx = l % 224; by = l / 224; }
    else { l -= 7168; in = w_out; outp = w_outT; R = DCAT; C = DM_;   bx = l % 32;  by = l / 32; }
    int c0 = bx * 32, r0 = by * 32;
    int x = threadIdx.x & 31, y = threadIdx.x >> 5;
    for (int i = 0; i < 32; i += 8)
        tile[y + i][x] = in[(size_t)(r0 + y + i) * C + (c0 + x)];
    __syncthreads();
    for (int i = 0; i < 32; i += 8)
        outp[(size_t)(c0 + y + i) * R + (r0 + x)] = (bf16)tile[x][y + i];
}

// ---------------- in-LN + token shift -> xs (bf16) ----------------
__global__ __launch_bounds__(256) void ln_shift(const float* __restrict__ x,
                                                const float* __restrict__ g,
                                                const float* __restrict__ bb,
                                                bf16* __restrict__ xs) {
    int tok = blockIdx.x;
    int b = tok / L_, l = tok % L_;
    const float* row = x + (size_t)tok * DM_;
    float vals[4];
    float s = 0.f, s2 = 0.f;
    for (int i = 0; i < 4; i++) {
        float v = row[threadIdx.x + i * 256];
        vals[i] = v; s += v; s2 += v * v;
    }
    __shared__ float red[2][4];
    for (int o = 32; o; o >>= 1) { s += __shfl_xor(s, o); s2 += __shfl_xor(s2, o); }
    int w = threadIdx.x >> 6;
    if ((threadIdx.x & 63) == 0) { red[0][w] = s; red[1][w] = s2; }
    __syncthreads();
    s  = red[0][0] + red[0][1] + red[0][2] + red[0][3];
    s2 = red[1][0] + red[1][1] + red[1][2] + red[1][3];
    float mean = s * (1.f / DM_);
    float var  = s2 * (1.f / DM_) - mean * mean;
    float rstd = rsqrtf(var + 1e-5f);
    for (int i = 0; i < 4; i++) {
        int c = threadIdx.x + i * 256;
        float y = (vals[i] - mean) * rstd * g[c] + bb[c];
        int shift = (c < 256) ? 1 : ((c >= 896) ? 2 : 0);
        int dl = l + shift;
        if (dl < L_) xs[((size_t)b * L_ + dl) * DM_ + c] = (bf16)y;
        if (l == 0 && shift) {
            xs[((size_t)b * L_ + 0) * DM_ + c] = (bf16)0.f;
            if (shift == 2) xs[((size_t)b * L_ + 1) * DM_ + c] = (bf16)0.f;
        }
    }
}

// ---------------- GEMM1: 256x128 tile, ping-pong LDS dbuf, 1 barrier/iter ----------------
__global__ __launch_bounds__(256, 2) void gemm1_k(const bf16* __restrict__ A,
                                                  const bf16* __restrict__ Bt,
                                                  bf16* __restrict__ C) {
    const int K = DM_, N = DPROJ_;
    int lin = blockIdx.x;                 // 896 blocks
    int chunk = lin >> 7, within = lin & 127;
    int m0 = (within >> 3) * 256;
    int n0 = (chunk * 8 + (within & 7)) * 128;
    __shared__ bf16 As[2][256 * 32];
    __shared__ bf16 Bs[2][128 * 32];
    int t = threadIdx.x, lane = t & 63, wave = t >> 6;
    int c = lane & 15, quad = lane >> 4;
    int wm = wave * 64;
    auto stage = [&](int k0, int bsel) {
        #pragma unroll
        for (int s = 0; s < 4; s++) {
            int f = s * 256 + t;
            int row = f >> 2, kp = (f & 3) * 8;
            g2l16(A + (size_t)(m0 + row) * K + k0 + kp, &As[bsel][f * 8]);
        }
        #pragma unroll
        for (int s = 0; s < 2; s++) {
            int f = s * 256 + t;
            int row = f >> 2, kp = (f & 3) * 8;
            g2l16(Bt + (size_t)(n0 + row) * K + k0 + kp, &Bs[bsel][f * 8]);
        }
    };
    floatx4 acc[4][8] = {};
    stage(0, 0);
    int buf = 0;
    for (int k0 = 0; k0 < K; k0 += 32) {
        __syncthreads();                       // drains prefetch issued LAST iter
        if (k0 + 32 < K) stage(k0 + 32, buf ^ 1);  // overlap with compute below
        bf16x8 af[4], bfr[8];
        #pragma unroll
        for (int i = 0; i < 4; i++)
            af[i] = *(const bf16x8*)&As[buf][(wm + i * 16 + c) * 32 + quad * 8];
        #pragma unroll
        for (int j = 0; j < 8; j++)
            bfr[j] = *(const bf16x8*)&Bs[buf][(j * 16 + c) * 32 + quad * 8];
        #pragma unroll
        for (int i = 0; i < 4; i++)
            #pragma unroll
            for (int j = 0; j < 8; j++)
                acc[i][j] = __builtin_amdgcn_mfma_f32_16x16x32_bf16(af[i], bfr[j], acc[i][j], 0, 0, 0);
        buf ^= 1;
    }
    #pragma unroll
    for (int i = 0; i < 4; i++)
        #pragma unroll
        for (int j = 0; j < 8; j++)
            #pragma unroll
            for (int r = 0; r < 4; r++) {
                int row = m0 + wm + i * 16 + quad * 4 + r;
                int col = n0 + j * 16 + c;
                C[(size_t)row * N + col] = (bf16)acc[i][j][r];
            }
}

// ---------------- GEMM2 split-K: 128x128, ping-pong dbuf; contiguous partials ----------------
__global__ __launch_bounds__(256) void gemm2_sk(const bf16* __restrict__ A,
                                                const bf16* __restrict__ Bt,
                                                float* __restrict__ P) {
    const int ldA = DCAT, N = DM_;
    int m0 = blockIdx.x * 128, n0 = blockIdx.y * 128, kz = blockIdx.z;
    const bf16* Ak = A + kz * 1024;
    const bf16* Btk = Bt + kz * 1024;
    float* C = P + (size_t)kz * NTOK * DM_;
    __shared__ bf16 As[2][128 * 32];
    __shared__ bf16 Bs[2][128 * 32];
    int t = threadIdx.x, lane = t & 63, wave = t >> 6;
    int c = lane & 15, quad = lane >> 4;
    int wm = (wave >> 1) * 64, wn = (wave & 1) * 64;
    auto stage = [&](int k0, int bsel) {
        #pragma unroll
        for (int s = 0; s < 2; s++) {
            int f = s * 256 + t;
            int row = f >> 2, kp = (f & 3) * 8;
            g2l16(Ak + (size_t)(m0 + row) * ldA + k0 + kp, &As[bsel][f * 8]);
            g2l16(Btk + (size_t)(n0 + row) * ldA + k0 + kp, &Bs[bsel][f * 8]);
        }
    };
    floatx4 acc[4][4] = {};
    stage(0, 0);
    int buf = 0;
    for (int k0 = 0; k0 < 1024; k0 += 32) {
        __syncthreads();
        if (k0 + 32 < 1024) stage(k0 + 32, buf ^ 1);
        bf16x8 af[4], bfr[4];
        #pragma unroll
        for (int i = 0; i < 4; i++)
            af[i] = *(const bf16x8*)&As[buf][(wm + i * 16 + c) * 32 + quad * 8];
        #pragma unroll
        for (int j = 0; j < 4; j++)
            bfr[j] = *(const bf16x8*)&Bs[buf][(wn + j * 16 + c) * 32 + quad * 8];
        #pragma unroll
        for (int i = 0; i < 4; i++)
            #pragma unroll
            for (int j = 0; j < 4; j++)
                acc[i][j] = __builtin_amdgcn_mfma_f32_16x16x32_bf16(af[i], bfr[j], acc[i][j], 0, 0, 0);
        buf ^= 1;
    }
    #pragma unroll
    for (int i = 0; i < 4; i++)
        #pragma unroll
        for (int j = 0; j < 4; j++)
            #pragma unroll
            for (int r = 0; r < 4; r++) {
                int row = m0 + wm + i * 16 + quad * 4 + r;
                int col = n0 + wn + j * 16 + c;
                C[(size_t)row * N + col] = acc[i][j][r];
            }
}

// ---------------- mid-LN fused: h -> Qp,Kp,Vn packed [b,h,L,64] + gated A2 ----------------
__global__ __launch_bounds__(256) void mid_ln_fused(const bf16* __restrict__ h,
                                                    const float* __restrict__ g,
                                                    const float* __restrict__ bb,
                                                    bf16* __restrict__ Qp,
                                                    bf16* __restrict__ Kp,
                                                    bf16* __restrict__ Vn,
                                                    bf16* __restrict__ A2) {
    int tok = blockIdx.x;
    int b = tok >> 11, l = tok & 2047;
    size_t base = (size_t)tok * DPROJ_;
    int t = threadIdx.x;
    float v[28];
    float s = 0.f, s2 = 0.f;
    for (int i = 0; i < 28; i++) {
        v[i] = (float)h[base + t + i * 256];
        s += v[i]; s2 += v[i] * v[i];
    }
    __shared__ float red[2][4];
    for (int o = 32; o; o >>= 1) { s += __shfl_xor(s, o); s2 += __shfl_xor(s2, o); }
    int w = t >> 6;
    if ((t & 63) == 0) { red[0][w] = s; red[1][w] = s2; }
    __syncthreads();
    s  = red[0][0] + red[0][1] + red[0][2] + red[0][3];
    s2 = red[1][0] + red[1][1] + red[1][2] + red[1][3];
    float mean = s * (1.f / DPROJ_);
    float var  = s2 * (1.f / DPROJ_) - mean * mean;
    float rstd = rsqrtf(var + 1e-5f);
    #pragma unroll
    for (int i = 0; i < 28; i++) {
        int c = t + i * 256;
        v[i] = (v[i] - mean) * rstd * g[c] + bb[c];
    }
    #pragma unroll
    for (int i = 0; i < 12; i++) {
        int c = t + i * 256;
        int sec = c >> 10;
        int cc = c & 1023;
        int hh = cc >> 6, d = cc & 63;
        size_t idx = (((size_t)b * HEADS_ + hh) * L_ + l) * DH_ + d;
        bf16* dst = (sec == 0) ? Qp : (sec == 1) ? Kp : Vn;
        dst[idx] = (bf16)v[i];
    }
    #pragma unroll
    for (int i = 12; i < 20; i++) {
        int c = t + i * 256;
        A2[(size_t)tok * DCAT + DM_ + (c - 3 * DM_)] = (bf16)(v[i] * v[i + 8]);
    }
}

// ---------------- Vn [b,h,L,64] -> Vt [b,h,64,L] ----------------
__global__ __launch_bounds__(256) void vt_pack(const bf16* __restrict__ Vn,
                                               bf16* __restrict__ Vt) {
    __shared__ bf16 tile[32][33];
    int bh = blockIdx.z;
    const bf16* in = Vn + (size_t)bh * L_ * DH_;
    bf16* out = Vt + (size_t)bh * DH_ * L_;
    int l0 = blockIdx.x * 32, d0 = blockIdx.y * 32;
    int x = threadIdx.x & 31, y = threadIdx.x >> 5;
    for (int i = 0; i < 32; i += 8)
        tile[y + i][x] = in[(size_t)(l0 + y + i) * DH_ + d0 + x];
    __syncthreads();
    for (int i = 0; i < 32; i += 8)
        out[(size_t)(d0 + y + i) * L_ + l0 + x] = tile[x][y + i];
}

// ---------------- flash attention v4: fixed-max softmax ----------------
__global__ __launch_bounds__(256, 4) void attn4(const bf16* __restrict__ Qp,
                                                const bf16* __restrict__ Kp,
                                                const bf16* __restrict__ Vt,
                                                const float* __restrict__ slopes,
                                                bf16* __restrict__ A2) {
    int hd = blockIdx.y, b = blockIdx.z;
    int lin = blockIdx.x + 32 * blockIdx.y + 512 * blockIdx.z;
    int xr = blockIdx.x;
    int qt = ((lin >> 8) & 1) ? (31 - xr) : xr;
    int q0 = qt * 64;
    int t = threadIdx.x, lane = t & 63, wave = t >> 6;
    int quad = lane >> 4, c = lane & 15;
    __shared__ bf16 Ks[2 * 64 * 32];
    __shared__ bf16 Vs[2 * 64 * 32];
    __shared__ bf16 Ps[4][16 * 72];
    int bh = b * HEADS_ + hd;
    const bf16* Qb = Qp + (size_t)bh * L_ * DH_;
    const bf16* Kb = Kp + (size_t)bh * L_ * DH_;
    const bf16* Vb = Vt + (size_t)bh * DH_ * L_;
    const float LOG2E = 1.44269504f;
    float slopeL2 = slopes[hd] * LOG2E;
    const float qscale = 0.125f * LOG2E;

    bf16x8 qf[2];
    int qrow = q0 + wave * 16 + c;
    qf[0] = *(const bf16x8*)(Qb + (size_t)qrow * DH_ + quad * 8);
    qf[1] = *(const bf16x8*)(Qb + (size_t)qrow * DH_ + 32 + quad * 8);
    floatx4 accO[4] = {};
    float lsum[4];
    float mrow[4];
    int i_row0 = q0 + wave * 16 + quad * 4;
    #pragma unroll
    for (int r = 0; r < 4; r++) {
        lsum[r] = 0.f;
        mrow[r] = slopeL2 * (float)(i_row0 + r) + 20.0f;
    }

    int row = t >> 2, kp = (t & 3) * 8;
    bf16* pw = &Ps[wave][0];
    bf16* pwr = pw + (quad * 4) * 72 + c;
    for (int j0 = 0; j0 <= q0; j0 += 64) {
        #pragma unroll
        for (int s = 0; s < 2; s++) {
            g2l16(Kb + (size_t)(j0 + row) * DH_ + s * 32 + kp, &Ks[(s * 256 + t) * 8]);
            g2l16(Vb + (size_t)row * L_ + j0 + s * 32 + kp, &Vs[(s * 256 + t) * 8]);
        }
        __syncthreads();

        bool diag = (j0 == q0);
        #pragma unroll
        for (int nt = 0; nt < 4; nt++) {
            floatx4 sacc = {};
            bf16x8 kf0 = *(const bf16x8*)&Ks[(nt * 16 + c) * 32 + quad * 8];
            bf16x8 kf1 = *(const bf16x8*)&Ks[2048 + (nt * 16 + c) * 32 + quad * 8];
            sacc = __builtin_amdgcn_mfma_f32_16x16x32_bf16(qf[0], kf0, sacc, 0, 0, 0);
            sacc = __builtin_amdgcn_mfma_f32_16x16x32_bf16(qf[1], kf1, sacc, 0, 0, 0);
            int j = j0 + nt * 16 + c;
            float aj = slopeL2 * (float)j;
            #pragma unroll
            for (int r = 0; r < 4; r++) {
                float p = exp2f(fmaf(sacc[r], qscale, aj) - mrow[r]);
                if (diag) p = (j <= i_row0 + r) ? p : 0.f;
                lsum[r] += p;
                pwr[r * 72 + nt * 16] = (bf16)p;
            }
        }
        bf16x8 pf0 = *(const bf16x8*)&pw[c * 72 + quad * 8];
        bf16x8 pf1 = *(const bf16x8*)&pw[c * 72 + 32 + quad * 8];
        #pragma unroll
        for (int nt = 0; nt < 4; nt++) {
            bf16x8 vf0 = *(const bf16x8*)&Vs[(nt * 16 + c) * 32 + quad * 8];
            bf16x8 vf1 = *(const bf16x8*)&Vs[2048 + (nt * 16 + c) * 32 + quad * 8];
            accO[nt] = __builtin_amdgcn_mfma_f32_16x16x32_bf16(pf0, vf0, accO[nt], 0, 0, 0);
            accO[nt] = __builtin_amdgcn_mfma_f32_16x16x32_bf16(pf1, vf1, accO[nt], 0, 0, 0);
        }
        __syncthreads();
    }
    #pragma unroll
    for (int r = 0; r < 4; r++) {
        float l = lsum[r];
        l += __shfl_xor(l, 1);
        l += __shfl_xor(l, 2);
        l += __shfl_xor(l, 4);
        l += __shfl_xor(l, 8);
        lsum[r] = 1.f / l;
    }
    #pragma unroll
    for (int r = 0; r < 4; r++) {
        size_t orow = (size_t)b * L_ + q0 + wave * 16 + quad * 4 + r;
        #pragma unroll
        for (int nt = 0; nt < 4; nt++)
            A2[orow * DCAT + hd * DH_ + nt * 16 + c] = (bf16)(accO[nt][r] * lsum[r]);
    }
}

// ---------------- out-LN over sum of 3 contiguous split-K partials ----------------
__global__ __launch_bounds__(256) void out_ln3(const float* __restrict__ P,
                                               const float* __restrict__ g,
                                               const float* __restrict__ bb,
                                               float* __restrict__ out) {
    size_t base = (size_t)blockIdx.x * DM_;
    const size_t stride = (size_t)NTOK * DM_;
    float v[4];
    float s = 0.f, s2 = 0.f;
    for (int i = 0; i < 4; i++) {
        size_t idx = base + threadIdx.x + i * 256;
        v[i] = P[idx] + P[idx + stride] + P[idx + 2 * stride];
        s += v[i]; s2 += v[i] * v[i];
    }
    __shared__ float red[2][4];
    for (int o = 32; o; o >>= 1) { s += __shfl_xor(s, o); s2 += __shfl_xor(s2, o); }
    int w = threadIdx.x >> 6;
    if ((threadIdx.x & 63) == 0) { red[0][w] = s; red[1][w] = s2; }
    __syncthreads();
    s  = red[0][0] + red[0][1] + red[0][2] + red[0][3];
    s2 = red[1][0] + red[1][1] + red[1][2] + red[1][3];
    float mean = s * (1.f / DM_);
    float var  = s2 * (1.f / DM_) - mean * mean;
    float rstd = rsqrtf(var + 1e-5f);
    for (int i = 0; i < 4; i++) {
        int c = threadIdx.x + i * 256;
        out[base + c] = (v[i] - mean) * rstd * g[c] + bb[c];
    }
}

extern "C" void kernel_launch(void* const* d_in, const int* in_sizes, int n_in,
                              void* d_out, int out_size, void* d_ws, size_t ws_size,
                              hipStream_t stream) {
    const float* x     = (const float*)d_in[0];
    const float* in_g  = (const float*)d_in[1];
    const float* in_b  = (const float*)d_in[2];
    const float* mid_g = (const float*)d_in[3];
    const float* mid_b = (const float*)d_in[4];
    const float* out_g = (const float*)d_in[5];
    const float* out_b = (const float*)d_in[6];
    const float* w_in  = (const float*)d_in[7];
    const float* w_out = (const float*)d_in[8];
    const float* slopes = (const float*)d_in[9];
    float* out = (float*)d_out;

    char* ws = (char*)d_ws;
    size_t off = 0;
    auto alloc = [&](size_t n) { char* p = ws + off; off += (n + 255) & ~(size_t)255; return p; };
    bf16* w_inT  = (bf16*)alloc((size_t)DPROJ_ * DM_ * 2);   // 14.7 MB
    bf16* w_outT = (bf16*)alloc((size_t)DM_ * DCAT * 2);     // 6.3 MB
    bf16* xs     = (bf16*)alloc((size_t)NTOK * DM_ * 2);     // 8.4 MB (reused as Vt)
    bf16* h      = (bf16*)alloc((size_t)NTOK * DPROJ_ * 2);  // 58.7 MB (reused: 3 contig f32 partials)
    bf16* A2     = (bf16*)alloc((size_t)NTOK * DCAT * 2);    // 25.2 MB
    bf16* Qp     = (bf16*)alloc((size_t)NTOK * DM_ * 2);     // 8.4 MB
    bf16* Kp     = (bf16*)alloc((size_t)NTOK * DM_ * 2);     // 8.4 MB
    bf16* Vn     = (bf16*)alloc((size_t)NTOK * DM_ * 2);     // 8.4 MB
    bf16* Vt = xs;            // xs dead after gemm1
    float* P = (float*)h;     // h dead after mid_ln_fused; gemm2 runs after attn

    hipLaunchKernelGGL(transpose_both, dim3(7168 + 3072), dim3(256), 0, stream,
                       w_in, w_out, w_inT, w_outT);
    hipLaunchKernelGGL(ln_shift, dim3(NTOK), dim3(256), 0, stream, x, in_g, in_b, xs);
    hipLaunchKernelGGL(gemm1_k, dim3(896), dim3(256), 0, stream, xs, w_inT, h);
    hipLaunchKernelGGL(mid_ln_fused, dim3(NTOK), dim3(256), 0, stream, h, mid_g, mid_b,
                       Qp, Kp, Vn, A2);
    hipLaunchKernelGGL(vt_pack, dim3(L_ / 32, DH_ / 32, B_ * HEADS_), dim3(256), 0, stream, Vn, Vt);
    hipLaunchKernelGGL(attn4, dim3(32, HEADS_, B_), dim3(256), 0, stream, Qp, Kp, Vt, slopes, A2);
    hipLaunchKernelGGL(gemm2_sk, dim3(NTOK / 128, DM_ / 128, 3), dim3(256), 0, stream,
                       A2, w_outT, P);
    hipLaunchKernelGGL(out_ln3, dim3(NTOK), dim3(256), 0, stream, P, out_g, out_b, out);
}